// Round 12
// baseline (371.921 us; speedup 1.0000x reference)
//
#include <hip/hip_runtime.h>
#include <hip/hip_fp16.h>

#define DD 8
#define HH 256
#define CH 8192          // edges per chunk: 41-edge runs/bin -> full-line scatter writes
#define PAYBITS 17       // N <= 131072
#define PAYMASK 0x1FFFF
#define FPITCH 20        // fwd pair-pack pitch (uints): 80B, 16B-aligned, 2-way banks
#define BPITCH 28        // bwd pair-pack pitch (uints): 112B, 16B-aligned, 2-way banks

// R11: 302.9us, all kernels < 41us. R12: CSR-build restructure -- k_part2 was
// counting per-chunk bins that k_coarse already computed. Now coarse stores
// per-chunk hists; cscan derives deterministic per-(chunk,bin) bases; part2
// is a single scatter pass with no count pass, no cCur atomics, and chunks
// write disjoint ranges. Also deletes the gHist memset dispatch.

typedef _Float16 h2f __attribute__((ext_vector_type(2)));

static __device__ __forceinline__ float dot2u(unsigned w, h2f z, float c) {
#if __has_builtin(__builtin_amdgcn_fdot2)
    return __builtin_amdgcn_fdot2(__builtin_bit_cast(h2f, w), z, c, false);
#else
    __half2 h = __builtin_bit_cast(__half2, w);
    float2 f = __half22float2(h);
    return fmaf(f.y, (float)z[1], fmaf(f.x, (float)z[0], c));
#endif
}
static __device__ __forceinline__ h2f pkh(float a, float b) {
    h2f r; r[0] = (_Float16)a; r[1] = (_Float16)b; return r;
}
static __device__ __forceinline__ unsigned pk2(float a, float b) {
    __half2 hh; hh.x = __float2half(a); hh.y = __float2half(b);
    return *(unsigned*)&hh;
}

// ---- DPP lane-group sum (VALU pipe; no LDS round-trips) ----
template <int CTRL>
static __device__ __forceinline__ float dppadd(float x) {
    int y = __builtin_amdgcn_update_dpp(0, __builtin_bit_cast(int, x),
                                        CTRL, 0xF, 0xF, true);
    return x + __builtin_bit_cast(float, y);
}
static __device__ __forceinline__ void red16(float a[8]) {
#pragma unroll
    for (int k = 0; k < 8; k++) a[k] = dppadd<0xB1>(a[k]);   // xor1
#pragma unroll
    for (int k = 0; k < 8; k++) a[k] = dppadd<0x4E>(a[k]);   // xor2
#pragma unroll
    for (int k = 0; k < 8; k++) a[k] = dppadd<0x141>(a[k]);  // row_half_mirror
#pragma unroll
    for (int k = 0; k < 8; k++) a[k] = dppadd<0x140>(a[k]);  // row_mirror
}
// sum over aligned 8-lane group (result in all 8 lanes)
static __device__ __forceinline__ void red8(float a[8]) {
#pragma unroll
    for (int k = 0; k < 8; k++) a[k] = dppadd<0xB1>(a[k]);
#pragma unroll
    for (int k = 0; k < 8; k++) a[k] = dppadd<0x4E>(a[k]);
#pragma unroll
    for (int k = 0; k < 8; k++) a[k] = dppadd<0x141>(a[k]);
}

// ============================ CSR construction ==============================

// per-chunk 256-bin histograms for both dirs -> global (coalesced)
__global__ void k_coarse(const int* __restrict__ src, const int* __restrict__ dst,
                         int* __restrict__ cHistIn, int* __restrict__ cHistOut,
                         int E) {
    __shared__ int hIn[256], hOut[256];
    hIn[threadIdx.x] = 0; hOut[threadIdx.x] = 0;
    __syncthreads();
    int lo = blockIdx.x * CH;
    int hi = min(lo + CH, E);
    for (int i = lo + threadIdx.x; i < hi; i += blockDim.x) {
        atomicAdd(&hIn[dst[i] >> 9], 1);
        atomicAdd(&hOut[src[i] >> 9], 1);
    }
    __syncthreads();
    cHistIn [blockIdx.x * 256 + threadIdx.x] = hIn[threadIdx.x];
    cHistOut[blockIdx.x * 256 + threadIdx.x] = hOut[threadIdx.x];
}

// single block: per-bin totals -> exclusive bin scan -> in-place chunk bases
__global__ void k_cscan(int* __restrict__ cHistIn, int* __restrict__ cHistOut,
                        int* __restrict__ cStartIn, int* __restrict__ cStartOut,
                        int NB, int NC, int E) {
    __shared__ int s[256];
    int tid = threadIdx.x;
#pragma unroll
    for (int dir = 0; dir < 2; dir++) {
        int* cH = dir ? cHistOut : cHistIn;
        int* cs = dir ? cStartOut : cStartIn;
        // 1) per-bin total over chunks (coalesced)
        int tot = 0;
        for (int c = 0; c < NC; c++) tot += cH[c * 256 + tid];
        // 2) exclusive scan over bins
        s[tid] = tot;
        __syncthreads();
        for (int off = 1; off < 256; off <<= 1) {
            int t = (tid >= off) ? s[tid - off] : 0;
            __syncthreads();
            s[tid] += t;
            __syncthreads();
        }
        int run = s[tid] - tot;          // exclusive bin start
        if (tid < NB) cs[tid] = run;
        if (tid == NB || (tid == 255 && NB > 255)) cs[NB] = E;
        if (tid == 0) cs[NB] = E;        // safe: NB < 256 here
        // 3) in-place: cH[c][bin] <- base for chunk c
        for (int c = 0; c < NC; c++) {
            int h = cH[c * 256 + tid];
            cH[c * 256 + tid] = run;
            run += h;
        }
        __syncthreads();
    }
}

// single scatter pass: LDS cursors seeded from precomputed chunk bases
__global__ void k_part2(const int* __restrict__ src, const int* __restrict__ dst,
                        const int* __restrict__ cBaseIn, const int* __restrict__ cBaseOut,
                        int* __restrict__ P_in, int* __restrict__ P_out, int E) {
    int dir = blockIdx.y;
    const int* key   = dir ? src : dst;
    const int* pay   = dir ? dst : src;
    const int* cBase = dir ? cBaseOut : cBaseIn;
    int* P           = dir ? P_out    : P_in;
    __shared__ int h[256];
    h[threadIdx.x] = cBase[blockIdx.x * 256 + threadIdx.x];
    __syncthreads();
    int lo = blockIdx.x * CH;
    int hi = min(lo + CH, E);
    for (int i = lo + threadIdx.x; i < hi; i += blockDim.x) {
        int k = key[i];
        int pos = atomicAdd(&h[k >> 9], 1);
        P[pos] = ((k & 511) << PAYBITS) | pay[i];
    }
}

__launch_bounds__(512)
__global__ void k_fine2(const int* __restrict__ cStartIn, const int* __restrict__ cStartOut,
                        const int* __restrict__ P_in, const int* __restrict__ P_out,
                        int* __restrict__ start_in, int* __restrict__ start_out,
                        int* __restrict__ csr_in, int* __restrict__ csr_out, int N) {
    int dir = blockIdx.y;
    const int* cStart = dir ? cStartOut : cStartIn;
    const int* P      = dir ? P_out     : P_in;
    int* start        = dir ? start_out : start_in;
    int* csr          = dir ? csr_out   : csr_in;
    __shared__ int cnt[512], scn[512];
    int b = blockIdx.x;
    int lo = cStart[b], hi = cStart[b + 1];
    cnt[threadIdx.x] = 0;
    __syncthreads();
    for (int i = lo + threadIdx.x; i < hi; i += 512)
        atomicAdd(&cnt[P[i] >> PAYBITS], 1);
    __syncthreads();
    int own = cnt[threadIdx.x];
    scn[threadIdx.x] = own;
    __syncthreads();
    for (int off = 1; off < 512; off <<= 1) {
        int t = (threadIdx.x >= off) ? scn[threadIdx.x - off] : 0;
        __syncthreads();
        scn[threadIdx.x] += t;
        __syncthreads();
    }
    int base = lo + scn[threadIdx.x] - own;
    int node = (b << 9) + threadIdx.x;
    if (node < N) start[node] = base;
    cnt[threadIdx.x] = base;   // reuse as cursor
    __syncthreads();
    for (int i = lo + threadIdx.x; i < hi; i += 512) {
        int p = P[i];
        int pos = atomicAdd(&cnt[p >> PAYBITS], 1);
        csr[pos] = p & PAYMASK;
    }
}

// ==== per-node prep (norms, masses, dHdP) + pair-packed fp16 weights =======
__global__ void k_prep(const float* __restrict__ q, const float* __restrict__ p,
                       const float* __restrict__ M,
                       const float* __restrict__ W1, const float* __restrict__ W2,
                       unsigned* __restrict__ Fp, unsigned* __restrict__ Bp,
                       int* __restrict__ start_in, int* __restrict__ start_out,
                       float* __restrict__ a, float* __restrict__ b,
                       __half2* __restrict__ hm, __half* __restrict__ qn,
                       float* __restrict__ out, int N, int E) {
    int t = blockIdx.x * blockDim.x + threadIdx.x;
    if (t == 0) { start_in[N] = E; start_out[N] = E; }
    if (t < 128) {                       // one thread packs one (j0, j0+16) pair
        int ci = t >> 4, l16 = t & 15;
        int j0 = ci * 32 + l16, j1 = j0 + 16;
        unsigned* F = Fp + t * FPITCH;
        unsigned* B = Bp + t * BPITCH;
#pragma unroll
        for (int k = 0; k < 4; k++) {
            unsigned c0 = pk2(W1[(2 * k) * HH + j0], W1[(2 * k + 1) * HH + j0]);
            unsigned c1 = pk2(W1[(2 * k) * HH + j1], W1[(2 * k + 1) * HH + j1]);
            F[k] = c0; F[4 + k] = c1; B[k] = c0; B[4 + k] = c1;
        }
#pragma unroll
        for (int k = 0; k < 8; k++)
            F[8 + k] = pk2(W2[j0 * DD + k], W2[j1 * DD + k]);
#pragma unroll
        for (int kk = 0; kk < 4; kk++) {
            B[8 + kk]  = pk2(W2[j0 * DD + 2 * kk], W2[j0 * DD + 2 * kk + 1]);
            B[12 + kk] = pk2(W2[j1 * DD + 2 * kk], W2[j1 * DD + 2 * kk + 1]);
        }
#pragma unroll
        for (int d = 0; d < 8; d++)
            B[16 + d] = pk2(W1[d * HH + j0], W1[d * HH + j1]);
        B[24] = 0; B[25] = 0; B[26] = 0; B[27] = 0;
    }
    int v = t;
    if (v >= N) return;
    int ei1 = (v + 1 < N) ? start_in[v + 1]  : E;
    int eo1 = (v + 1 < N) ? start_out[v + 1] : E;
    float din  = (float)(ei1 - start_in[v]);
    float dout = (float)(eo1 - start_out[v]);
    float av = 1.0f / sqrtf(dout > 0.f ? dout : 1.f);   // norm_src
    float bv = 1.0f / sqrtf(din  > 0.f ? din  : 1.f);   // norm_dst
    a[v] = av; b[v] = bv;
#pragma unroll
    for (int d = 0; d < DD; d++) {
        float m = M[(size_t)v * DD * DD + d * (DD + 1)];
        __half2 hmv;
        hmv.x = __float2half(0.f);
        hmv.y = __float2half(m);
        hm[(size_t)v * DD + d] = hmv;
        qn[(size_t)v * DD + d] = __float2half(av * q[(size_t)v * DD + d]);
        out[(size_t)v * 2 * DD + DD + d] = p[(size_t)v * DD + d] / m;  // dHdP
    }
}

// ------------------- record unpack/accumulate helpers -----------------------
static __device__ __forceinline__
void acc_h8(uint4 r, float acc[8]) {
    float2 f;
    f = __half22float2(*(__half2*)&r.x); acc[0] += f.x; acc[1] += f.y;
    f = __half22float2(*(__half2*)&r.y); acc[2] += f.x; acc[3] += f.y;
    f = __half22float2(*(__half2*)&r.z); acc[4] += f.x; acc[5] += f.y;
    f = __half22float2(*(__half2*)&r.w); acc[6] += f.x; acc[7] += f.y;
}

static __device__ __forceinline__
void unpack_hm(uint4 r0, uint4 r1, float h[8], float m[8]) {
    float2 f;
    f = __half22float2(*(__half2*)&r0.x); h[0] = f.x; m[0] = f.y;
    f = __half22float2(*(__half2*)&r0.y); h[1] = f.x; m[1] = f.y;
    f = __half22float2(*(__half2*)&r0.z); h[2] = f.x; m[2] = f.y;
    f = __half22float2(*(__half2*)&r0.w); h[3] = f.x; m[3] = f.y;
    f = __half22float2(*(__half2*)&r1.x); h[4] = f.x; m[4] = f.y;
    f = __half22float2(*(__half2*)&r1.y); h[5] = f.x; m[5] = f.y;
    f = __half22float2(*(__half2*)&r1.z); h[6] = f.x; m[6] = f.y;
    f = __half22float2(*(__half2*)&r1.w); h[7] = f.x; m[7] = f.y;
}

// gather full half8 records over csr range into acc[8]
static __device__ __forceinline__
void gather_h8(const int* __restrict__ csr, const __half* __restrict__ x,
               int e, int e1, float acc[8]) {
    for (; e + 3 < e1; e += 4) {
        int u0 = csr[e], u1 = csr[e + 1], u2 = csr[e + 2], u3 = csr[e + 3];
        uint4 r0 = *(const uint4*)(x + (size_t)u0 * DD);
        uint4 r1 = *(const uint4*)(x + (size_t)u1 * DD);
        uint4 r2 = *(const uint4*)(x + (size_t)u2 * DD);
        uint4 r3 = *(const uint4*)(x + (size_t)u3 * DD);
        acc_h8(r0, acc); acc_h8(r1, acc); acc_h8(r2, acc); acc_h8(r3, acc);
    }
    for (; e < e1; e++) {
        uint4 r = *(const uint4*)(x + (size_t)csr[e] * DD);
        acc_h8(r, acc);
    }
}

// ===== FUSED: agg1 = AggIn(qn) + MLP forward, 16 lanes/node, pair-dot2 =====
__launch_bounds__(256)
__global__ void k_agg_mlp_fwd(const int* __restrict__ start, const int* __restrict__ csr,
                              const __half* __restrict__ qn,
                              const float* __restrict__ a, const float* __restrict__ b,
                              const unsigned* __restrict__ Fp, const float* __restrict__ b1,
                              float* __restrict__ agg1, __half* __restrict__ ya, int N) {
    __shared__ unsigned sF[128 * FPITCH];   // 10 KB
    __shared__ float sb1[HH];
    for (int i = threadIdx.x; i < 128 * FPITCH; i += 256) sF[i] = Fp[i];
    for (int i = threadIdx.x; i < HH; i += 256) sb1[i] = b1[i];
    __syncthreads();
    int t = blockIdx.x * 256 + threadIdx.x;
    int v = t >> 4, l16 = t & 15, sub = (t >> 3) & 1, d = t & 7;
    if (v >= N) return;
    int e0 = start[v], e1 = start[v + 1];
    float ag[DD] = {0.f, 0.f, 0.f, 0.f, 0.f, 0.f, 0.f, 0.f};
    for (int e = e0 + l16; e < e1; e += 16) {
        uint4 r = *(const uint4*)(qn + (size_t)csr[e] * DD);
        acc_h8(r, ag);
    }
    red16(ag);
    if (l16 < 2) {
        float4 val = l16 ? make_float4(ag[4], ag[5], ag[6], ag[7])
                         : make_float4(ag[0], ag[1], ag[2], ag[3]);
        ((float4*)(agg1 + (size_t)v * DD))[l16] = val;
    }
    float bv = b[v];
    h2f zh[4];
#pragma unroll
    for (int k = 0; k < 4; k++) zh[k] = pkh(bv * ag[2 * k], bv * ag[2 * k + 1]);
    float acc[DD] = {0.f, 0.f, 0.f, 0.f, 0.f, 0.f, 0.f, 0.f};
#pragma unroll
    for (int ci = 0; ci < 8; ci++) {
        int pid = ci * 16 + l16;
        const uint4* pw = (const uint4*)(sF + pid * FPITCH);
        uint4 w1a = pw[0], w1b = pw[1], w2p0 = pw[2], w2p1 = pw[3];
        int j0 = ci * 32 + l16;
        float u0 = sb1[j0], u1 = sb1[j0 + 16];
        u0 = dot2u(w1a.x, zh[0], u0); u0 = dot2u(w1a.y, zh[1], u0);
        u0 = dot2u(w1a.z, zh[2], u0); u0 = dot2u(w1a.w, zh[3], u0);
        u1 = dot2u(w1b.x, zh[0], u1); u1 = dot2u(w1b.y, zh[1], u1);
        u1 = dot2u(w1b.z, zh[2], u1); u1 = dot2u(w1b.w, zh[3], u1);
        h2f hh = pkh(fmaxf(u0, 0.f), fmaxf(u1, 0.f));
        acc[0] = dot2u(w2p0.x, hh, acc[0]); acc[1] = dot2u(w2p0.y, hh, acc[1]);
        acc[2] = dot2u(w2p0.z, hh, acc[2]); acc[3] = dot2u(w2p0.w, hh, acc[3]);
        acc[4] = dot2u(w2p1.x, hh, acc[4]); acc[5] = dot2u(w2p1.y, hh, acc[5]);
        acc[6] = dot2u(w2p1.z, hh, acc[6]); acc[7] = dot2u(w2p1.w, hh, acc[7]);
    }
    red16(acc);
    float yl = acc[0];
#pragma unroll
    for (int k = 1; k < DD; k++) yl = (d == k) ? acc[k] : yl;
    if (!sub) ya[(size_t)v * DD + d] = __float2half(a[v] * yl);
}

// h = b*AggIn(ya) + b2 + q  -> .x halves of hm records; 8 thr/node
__launch_bounds__(256)
__global__ void k_h_node(const int* __restrict__ start, const int* __restrict__ csr,
                         const __half* __restrict__ ya, const float* __restrict__ b,
                         const float* __restrict__ q, const float* __restrict__ b2,
                         __half2* __restrict__ hm, int N) {
    int t = blockIdx.x * 256 + threadIdx.x;
    int v = t >> 3, sub = t & 7;
    if (v >= N) return;
    int e0 = start[v], e1 = start[v + 1], len = e1 - e0;
    int lo = e0 + (len * sub) / 8, hi = e0 + (len * (sub + 1)) / 8;
    float acc[8] = {0.f, 0.f, 0.f, 0.f, 0.f, 0.f, 0.f, 0.f};
    gather_h8(csr, ya, lo, hi, acc);
    red8(acc);
    if (sub == 0) {
        float bv = b[v];
        const float4* qp = (const float4*)(q + (size_t)v * DD);
        float4 q0 = qp[0], q1 = qp[1];
        float hq[8] = {q0.x, q0.y, q0.z, q0.w, q1.x, q1.y, q1.z, q1.w};
        __half2* hp = hm + (size_t)v * DD;
#pragma unroll
        for (int k = 0; k < DD; k++) {
            float hval = fmaf(bv, acc[k], b2[k] + hq[k]);
            __half2 cur = hp[k];
            cur.x = __float2half(hval);
            hp[k] = cur;
        }
    }
}

// gravity gradient: 8 threads/node (dir x quarter-range)
__launch_bounds__(256)
__global__ void k_gh4(const int* __restrict__ start_in, const int* __restrict__ csr_in,
                      const int* __restrict__ start_out, const int* __restrict__ csr_out,
                      const __half2* __restrict__ hm,
                      const float* __restrict__ b, const float* __restrict__ grav,
                      float* __restrict__ gh, __half* __restrict__ bgh, int N) {
    int t = blockIdx.x * 256 + threadIdx.x;
    int v = t >> 3, sub = t & 7, dir = sub >> 2, qr = sub & 3;
    if (v >= N) return;
    const uint4* srec = (const uint4*)(hm + (size_t)v * DD);
    uint4 s0 = srec[0], s1 = srec[1];
    float hv[8], mv[8];
    unpack_hm(s0, s1, hv, mv);
    const int* start = dir ? start_out : start_in;
    const int* csr   = dir ? csr_out   : csr_in;
    int e0 = start[v], e1 = start[v + 1], len = e1 - e0;
    int e  = e0 + (len * qr) / 4;
    int hi = e0 + (len * (qr + 1)) / 4;
    float coef = -0.5f * grav[0];
    float acc[8] = {0.f, 0.f, 0.f, 0.f, 0.f, 0.f, 0.f, 0.f};
    for (; e + 1 < hi; e += 2) {
        int u0 = csr[e], u1 = csr[e + 1];
        const uint4* r0p = (const uint4*)(hm + (size_t)u0 * DD);
        const uint4* r1p = (const uint4*)(hm + (size_t)u1 * DD);
        uint4 x0 = r0p[0], x1 = r0p[1], y0 = r1p[0], y1 = r1p[1];
        float hu0[8], mu0[8], hu1[8], mu1[8];
        unpack_hm(x0, x1, hu0, mu0);
        unpack_hm(y0, y1, hu1, mu1);
        float d0[8], d1[8];
        float e20 = 0.f, S0 = 0.f, e21 = 0.f, S1 = 0.f;
#pragma unroll
        for (int k = 0; k < 8; k++) {
            d0[k] = hv[k] - hu0[k];
            d1[k] = hv[k] - hu1[k];
            e20 = fmaf(d0[k], d0[k], e20);
            e21 = fmaf(d1[k], d1[k], e21);
            S0 = fmaf(mv[k], mu0[k], S0);
            S1 = fmaf(mv[k], mu1[k], S1);
        }
        float r0 = rsqrtf(e20), r1 = rsqrtf(e21);
        float c0 = coef * S0 * r0 * r0 * r0;
        float c1 = coef * S1 * r1 * r1 * r1;
#pragma unroll
        for (int k = 0; k < 8; k++)
            acc[k] = fmaf(c0, d0[k], fmaf(c1, d1[k], acc[k]));
    }
    if (e < hi) {
        int u = csr[e];
        const uint4* rp = (const uint4*)(hm + (size_t)u * DD);
        uint4 x0 = rp[0], x1 = rp[1];
        float hu[8], mu[8];
        unpack_hm(x0, x1, hu, mu);
        float df[8];
        float e2 = 0.f, S = 0.f;
#pragma unroll
        for (int k = 0; k < 8; k++) {
            df[k] = hv[k] - hu[k];
            e2 = fmaf(df[k], df[k], e2);
            S = fmaf(mv[k], mu[k], S);
        }
        float r = rsqrtf(e2);
        float c = coef * S * r * r * r;
#pragma unroll
        for (int k = 0; k < 8; k++) acc[k] = fmaf(c, df[k], acc[k]);
    }
    red8(acc);   // combine the 8 subset threads via DPP
    if (sub == 0) {
        float4* gp = (float4*)(gh + (size_t)v * DD);
        gp[0] = make_float4(acc[0], acc[1], acc[2], acc[3]);
        gp[1] = make_float4(acc[4], acc[5], acc[6], acc[7]);
        float bv = b[v];
        __half2* bp = (__half2*)(bgh + (size_t)v * DD);
        bp[0] = __floats2half2_rn(bv * acc[0], bv * acc[1]);
        bp[1] = __floats2half2_rn(bv * acc[2], bv * acc[3]);
        bp[2] = __floats2half2_rn(bv * acc[4], bv * acc[5]);
        bp[3] = __floats2half2_rn(bv * acc[6], bv * acc[7]);
    }
}

// ===== FUSED: gq = AggOut(bgh) + MLP backward, 16 lanes/node, pair-dot2 =====
__launch_bounds__(256)
__global__ void k_bgh_mlp_bwd(const int* __restrict__ start, const int* __restrict__ csr,
                              const __half* __restrict__ bgh,
                              const float* __restrict__ agg1,
                              const float* __restrict__ a, const float* __restrict__ b,
                              const unsigned* __restrict__ Bp, const float* __restrict__ b1,
                              __half* __restrict__ gz1b, int N) {
    __shared__ unsigned sB[128 * BPITCH];   // 14 KB
    __shared__ float sb1[HH];
    for (int i = threadIdx.x; i < 128 * BPITCH; i += 256) sB[i] = Bp[i];
    for (int i = threadIdx.x; i < HH; i += 256) sb1[i] = b1[i];
    __syncthreads();
    int t = blockIdx.x * 256 + threadIdx.x;
    int v = t >> 4, l16 = t & 15, sub = (t >> 3) & 1, d = t & 7;
    if (v >= N) return;
    int e0 = start[v], e1 = start[v + 1];
    float gq[DD] = {0.f, 0.f, 0.f, 0.f, 0.f, 0.f, 0.f, 0.f};
    for (int e = e0 + l16; e < e1; e += 16) {
        uint4 r = *(const uint4*)(bgh + (size_t)csr[e] * DD);
        acc_h8(r, gq);
    }
    red16(gq);
    float bv = b[v], av = a[v];
    const float4* ap = (const float4*)(agg1 + (size_t)v * DD);
    float4 a0 = ap[0], a1 = ap[1];
    h2f zh[4], gqh[4];
    zh[0] = pkh(bv * a0.x, bv * a0.y); zh[1] = pkh(bv * a0.z, bv * a0.w);
    zh[2] = pkh(bv * a1.x, bv * a1.y); zh[3] = pkh(bv * a1.z, bv * a1.w);
#pragma unroll
    for (int k = 0; k < 4; k++) gqh[k] = pkh(gq[2 * k], gq[2 * k + 1]);
    float gz[DD] = {0.f, 0.f, 0.f, 0.f, 0.f, 0.f, 0.f, 0.f};
#pragma unroll
    for (int ci = 0; ci < 8; ci++) {
        int pid = ci * 16 + l16;
        const uint4* pw = (const uint4*)(sB + pid * BPITCH);
        uint4 w1a = pw[0], w1b = pw[1], w2r0 = pw[2], w2r1 = pw[3];
        uint4 g0p = pw[4], g1p = pw[5];
        int j0 = ci * 32 + l16;
        float u0 = sb1[j0], u1 = sb1[j0 + 16];
        u0 = dot2u(w1a.x, zh[0], u0); u0 = dot2u(w1a.y, zh[1], u0);
        u0 = dot2u(w1a.z, zh[2], u0); u0 = dot2u(w1a.w, zh[3], u0);
        u1 = dot2u(w1b.x, zh[0], u1); u1 = dot2u(w1b.y, zh[1], u1);
        u1 = dot2u(w1b.z, zh[2], u1); u1 = dot2u(w1b.w, zh[3], u1);
        float ga0 = dot2u(w2r0.x, gqh[0], 0.f);
        ga0 = dot2u(w2r0.y, gqh[1], ga0);
        ga0 = dot2u(w2r0.z, gqh[2], ga0);
        ga0 = dot2u(w2r0.w, gqh[3], ga0);
        float ga1 = dot2u(w2r1.x, gqh[0], 0.f);
        ga1 = dot2u(w2r1.y, gqh[1], ga1);
        ga1 = dot2u(w2r1.z, gqh[2], ga1);
        ga1 = dot2u(w2r1.w, gqh[3], ga1);
        float g0 = (u0 > 0.f) ? av * ga0 : 0.f;
        float g1 = (u1 > 0.f) ? av * ga1 : 0.f;
        h2f gg = pkh(g0, g1);
        gz[0] = dot2u(g0p.x, gg, gz[0]); gz[1] = dot2u(g0p.y, gg, gz[1]);
        gz[2] = dot2u(g0p.z, gg, gz[2]); gz[3] = dot2u(g0p.w, gg, gz[3]);
        gz[4] = dot2u(g1p.x, gg, gz[4]); gz[5] = dot2u(g1p.y, gg, gz[5]);
        gz[6] = dot2u(g1p.z, gg, gz[6]); gz[7] = dot2u(g1p.w, gg, gz[7]);
    }
    red16(gz);
    float out_l = gz[0];
#pragma unroll
    for (int k = 1; k < DD; k++) out_l = (d == k) ? gz[k] : out_l;
    if (!sub) gz1b[(size_t)v * DD + d] = __float2half(bv * out_l);
}

// out[:, :D] = gh + a * AggOut(gz1b); 8 thr/node
__launch_bounds__(256)
__global__ void k_out_node(const int* __restrict__ start, const int* __restrict__ csr,
                           const __half* __restrict__ gz1b, const float* __restrict__ gh,
                           const float* __restrict__ a, float* __restrict__ out, int N) {
    int t = blockIdx.x * 256 + threadIdx.x;
    int v = t >> 3, sub = t & 7;
    if (v >= N) return;
    int e0 = start[v], e1 = start[v + 1], len = e1 - e0;
    int lo = e0 + (len * sub) / 8, hi = e0 + (len * (sub + 1)) / 8;
    float acc[8] = {0.f, 0.f, 0.f, 0.f, 0.f, 0.f, 0.f, 0.f};
    gather_h8(csr, gz1b, lo, hi, acc);
    red8(acc);
    if (sub == 0) {
        float av = a[v];
        const float4* gp = (const float4*)(gh + (size_t)v * DD);
        float4 g0 = gp[0], g1 = gp[1];
        float4* op = (float4*)(out + (size_t)v * 2 * DD);
        op[0] = make_float4(fmaf(av, acc[0], g0.x), fmaf(av, acc[1], g0.y),
                            fmaf(av, acc[2], g0.z), fmaf(av, acc[3], g0.w));
        op[1] = make_float4(fmaf(av, acc[4], g1.x), fmaf(av, acc[5], g1.y),
                            fmaf(av, acc[6], g1.z), fmaf(av, acc[7], g1.w));
    }
}

// ============================== launch =====================================

extern "C" void kernel_launch(void* const* d_in, const int* in_sizes, int n_in,
                              void* d_out, int out_size, void* d_ws, size_t ws_size,
                              hipStream_t stream) {
    const float* q    = (const float*)d_in[0];
    const float* p    = (const float*)d_in[1];
    const float* M    = (const float*)d_in[2];
    const int*   src  = (const int*)d_in[3];
    const int*   dst  = (const int*)d_in[4];
    const float* W1   = (const float*)d_in[5];
    const float* b1   = (const float*)d_in[6];
    const float* W2   = (const float*)d_in[7];
    const float* b2   = (const float*)d_in[8];
    const float* grav = (const float*)d_in[9];
    float* out = (float*)d_out;

    int N = in_sizes[0] / DD;
    int E = in_sizes[3];
    size_t n = (size_t)N;
    int NB = (N + 511) >> 9;
    int NC = (E + CH - 1) / CH;

    // ---- data region (46N 4-byte words) ----
    float*   ws   = (float*)d_ws;
    float*   a_   = ws;             // N
    float*   b_   = ws + n;         // N
    __half*  qn   = (__half*)(ws + 2 * n);    // 8N half (4N words; region keeps 8N)
    float*   agg1 = ws + 10 * n;    // 8N f32 (live through bwd)
    float*   gh   = ws + 18 * n;    // 8N f32
    __half2* hm   = (__half2*)(ws + 26 * n);  // 8N half2 (8N words)
    __half*  ya   = (__half*)(ws + 34 * n);   // 8N half (4N words)
    __half*  bgh  = (__half*)(ws + 38 * n);   // 8N half (4N words)
    __half*  gz1b = (__half*)(ws + 42 * n);   // 8N half (4N words)

    // ---- int region ----
    int* iw        = (int*)(ws + 46 * n);
    int* csr_in    = iw;                       // E
    int* csr_out   = iw + (size_t)E;           // E
    int* start_in  = iw + 2 * (size_t)E;       // N+1
    int* start_out = start_in + n + 1;         // N+1
    int* cStartIn  = start_out + n + 1;        // NB+1
    int* cStartOut = cStartIn + NB + 1;        // NB+1
    int* iwEnd     = cStartOut + NB + 1;
    unsigned* Fp   = (unsigned*)iwEnd;         // 128*FPITCH = 2560 uints
    unsigned* Bp   = Fp + 128 * FPITCH;        // 128*BPITCH = 3584 uints
    int* cHistIn   = (int*)(Bp + 128 * BPITCH);  // NC*256 (becomes cBaseIn)
    int* cHistOut  = cHistIn + (size_t)NC * 256; // NC*256 (becomes cBaseOut)
    int* intAfter  = cHistOut + (size_t)NC * 256;
    // partition scratch: both dirs alias the data region (dead during build)
    int* P_in  = (E <= 16 * (long long)n) ? (int*)ws            : intAfter;
    int* P_out = (E <= 16 * (long long)n) ? (int*)(ws + 16 * n) : intAfter + E;

    const int tb = 256;
    int gbN  = (N + tb - 1) / tb;
    int gb8  = (int)((8 * n + tb - 1) / tb);   // 8 threads/node
    int gb16 = (int)((16 * n + tb - 1) / tb);  // 16 lanes/node

    // CSR build (no memset needed: cHist fully written by k_coarse)
    k_coarse  <<<NC, tb, 0, stream>>>(src, dst, cHistIn, cHistOut, E);
    k_cscan   <<<1, 256, 0, stream>>>(cHistIn, cHistOut, cStartIn, cStartOut,
                                      NB, NC, E);
    k_part2   <<<dim3(NC, 2), tb, 0, stream>>>(src, dst, cHistIn, cHistOut,
                                               P_in, P_out, E);
    k_fine2   <<<dim3(NB, 2), 512, 0, stream>>>(cStartIn, cStartOut, P_in, P_out,
                                                start_in, start_out, csr_in, csr_out, N);
    k_prep    <<<gbN, tb, 0, stream>>>(q, p, M, W1, W2, Fp, Bp, start_in, start_out,
                                       a_, b_, hm, qn, out, N, E);

    // forward: [agg1 = AggIn(a*q)] + [ya = a*(relu((b*agg1)@W1+b1)@W2)] fused
    k_agg_mlp_fwd<<<gb16, tb, 0, stream>>>(start_in, csr_in, qn, a_, b_,
                                           Fp, b1, agg1, ya, N);
    // h = b * AggIn(ya) + b2 + q  -> .x halves of hm
    k_h_node  <<<gb8, tb, 0, stream>>>(start_in, csr_in, ya, b_, q, b2, hm, N);
    // gravity gradient (8 threads/node, full records in-thread)
    k_gh4     <<<gb8, tb, 0, stream>>>(start_in, csr_in, start_out, csr_out,
                                       hm, b_, grav, gh, bgh, N);
    // [gq = AggOut(bgh)] + [gz1b = b*((a*(gq@W2^T)*relu')@W1^T)] fused
    k_bgh_mlp_bwd<<<gb16, tb, 0, stream>>>(start_out, csr_out, bgh, agg1, a_, b_,
                                           Bp, b1, gz1b, N);
    // dHdQ = gh + a * AggOut(gz1b)
    k_out_node<<<gb8, tb, 0, stream>>>(start_out, csr_out, gz1b, gh, a_, out, N);
}

// Round 13
// 286.553 us; speedup vs baseline: 1.2979x; 1.2979x over previous
//
#include <hip/hip_runtime.h>
#include <hip/hip_fp16.h>

#define DD 8
#define HH 256
#define CH 8192          // edges per chunk: 41-edge runs/bin -> full-line scatter writes
#define PAYBITS 17       // N <= 131072
#define PAYMASK 0x1FFFF
#define FPITCH 20        // fwd pair-pack pitch (uints): 80B, 16B-aligned, 2-way banks
#define BPITCH 28        // bwd pair-pack pitch (uints): 112B, 16B-aligned, 2-way banks

// R12 post-mortem (PMC): single-block cscan looping 196 chunks serially =
// 97us (1-block latency-bound). R13: k_cscan1 parallelizes the per-bin
// chunk-scan across 512 blocks (one per dir x bin); k_cscan2 is the old
// cheap 256-bin scan. part2 keeps R12's single-pass scatter (seeds =
// chunk-local offset + binStart).

typedef _Float16 h2f __attribute__((ext_vector_type(2)));

static __device__ __forceinline__ float dot2u(unsigned w, h2f z, float c) {
#if __has_builtin(__builtin_amdgcn_fdot2)
    return __builtin_amdgcn_fdot2(__builtin_bit_cast(h2f, w), z, c, false);
#else
    __half2 h = __builtin_bit_cast(__half2, w);
    float2 f = __half22float2(h);
    return fmaf(f.y, (float)z[1], fmaf(f.x, (float)z[0], c));
#endif
}
static __device__ __forceinline__ h2f pkh(float a, float b) {
    h2f r; r[0] = (_Float16)a; r[1] = (_Float16)b; return r;
}
static __device__ __forceinline__ unsigned pk2(float a, float b) {
    __half2 hh; hh.x = __float2half(a); hh.y = __float2half(b);
    return *(unsigned*)&hh;
}

// ---- DPP lane-group sum (VALU pipe; no LDS round-trips) ----
template <int CTRL>
static __device__ __forceinline__ float dppadd(float x) {
    int y = __builtin_amdgcn_update_dpp(0, __builtin_bit_cast(int, x),
                                        CTRL, 0xF, 0xF, true);
    return x + __builtin_bit_cast(float, y);
}
static __device__ __forceinline__ void red16(float a[8]) {
#pragma unroll
    for (int k = 0; k < 8; k++) a[k] = dppadd<0xB1>(a[k]);   // xor1
#pragma unroll
    for (int k = 0; k < 8; k++) a[k] = dppadd<0x4E>(a[k]);   // xor2
#pragma unroll
    for (int k = 0; k < 8; k++) a[k] = dppadd<0x141>(a[k]);  // row_half_mirror
#pragma unroll
    for (int k = 0; k < 8; k++) a[k] = dppadd<0x140>(a[k]);  // row_mirror
}
// sum over aligned 8-lane group (result in all 8 lanes)
static __device__ __forceinline__ void red8(float a[8]) {
#pragma unroll
    for (int k = 0; k < 8; k++) a[k] = dppadd<0xB1>(a[k]);
#pragma unroll
    for (int k = 0; k < 8; k++) a[k] = dppadd<0x4E>(a[k]);
#pragma unroll
    for (int k = 0; k < 8; k++) a[k] = dppadd<0x141>(a[k]);
}

// ============================ CSR construction ==============================

// per-chunk 256-bin histograms for both dirs -> global (coalesced)
__global__ void k_coarse(const int* __restrict__ src, const int* __restrict__ dst,
                         int* __restrict__ cHistIn, int* __restrict__ cHistOut,
                         int E) {
    __shared__ int hIn[256], hOut[256];
    hIn[threadIdx.x] = 0; hOut[threadIdx.x] = 0;
    __syncthreads();
    int lo = blockIdx.x * CH;
    int hi = min(lo + CH, E);
    for (int i = lo + threadIdx.x; i < hi; i += blockDim.x) {
        atomicAdd(&hIn[dst[i] >> 9], 1);
        atomicAdd(&hOut[src[i] >> 9], 1);
    }
    __syncthreads();
    cHistIn [blockIdx.x * 256 + threadIdx.x] = hIn[threadIdx.x];
    cHistOut[blockIdx.x * 256 + threadIdx.x] = hOut[threadIdx.x];
}

// stage A: one block per (bin, dir) -- parallel scan over chunks for that bin.
// cH[c][bin] <- exclusive chunk-local offset; binTot[bin] <- bin total.
__global__ void k_cscan1(int* __restrict__ cHistIn, int* __restrict__ cHistOut,
                         int* __restrict__ binTotIn, int* __restrict__ binTotOut,
                         int NC) {
    int bin = blockIdx.x;
    int* cH = blockIdx.y ? cHistOut : cHistIn;
    int* bT = blockIdx.y ? binTotOut : binTotIn;
    __shared__ int s[256];
    int tid = threadIdx.x;
    int carry = 0;
    for (int base = 0; base < NC; base += 256) {
        int c = base + tid;
        int val = (c < NC) ? cH[(size_t)c * 256 + bin] : 0;
        s[tid] = val;
        __syncthreads();
        for (int off = 1; off < 256; off <<= 1) {
            int t = (tid >= off) ? s[tid - off] : 0;
            __syncthreads();
            s[tid] += t;
            __syncthreads();
        }
        int excl = s[tid] - val + carry;
        if (c < NC) cH[(size_t)c * 256 + bin] = excl;
        carry += s[255];
        __syncthreads();
    }
    if (tid == 0) bT[bin] = carry;
}

// stage B: single block, 256-bin exclusive scan of totals (no chunk loop)
__global__ void k_cscan2(const int* __restrict__ binTotIn, const int* __restrict__ binTotOut,
                         int* __restrict__ binStartIn, int* __restrict__ binStartOut,
                         int* __restrict__ cStartIn, int* __restrict__ cStartOut,
                         int NB, int E) {
    __shared__ int s[256];
    int tid = threadIdx.x;
#pragma unroll
    for (int dir = 0; dir < 2; dir++) {
        const int* bT = dir ? binTotOut : binTotIn;
        int* bS = dir ? binStartOut : binStartIn;
        int* cs = dir ? cStartOut : cStartIn;
        int v = bT[tid];
        s[tid] = v;
        __syncthreads();
        for (int off = 1; off < 256; off <<= 1) {
            int t = (tid >= off) ? s[tid - off] : 0;
            __syncthreads();
            s[tid] += t;
            __syncthreads();
        }
        int ex = s[tid] - v;
        bS[tid] = ex;
        if (tid < NB) cs[tid] = ex;
        if (tid == 0) cs[NB] = E;
        __syncthreads();
    }
}

// single scatter pass: LDS cursors = chunk-local offset + bin start
__global__ void k_part2(const int* __restrict__ src, const int* __restrict__ dst,
                        const int* __restrict__ cBaseIn, const int* __restrict__ cBaseOut,
                        const int* __restrict__ binStartIn, const int* __restrict__ binStartOut,
                        int* __restrict__ P_in, int* __restrict__ P_out, int E) {
    int dir = blockIdx.y;
    const int* key   = dir ? src : dst;
    const int* pay   = dir ? dst : src;
    const int* cBase = dir ? cBaseOut : cBaseIn;
    const int* bS    = dir ? binStartOut : binStartIn;
    int* P           = dir ? P_out    : P_in;
    __shared__ int h[256];
    h[threadIdx.x] = cBase[blockIdx.x * 256 + threadIdx.x] + bS[threadIdx.x];
    __syncthreads();
    int lo = blockIdx.x * CH;
    int hi = min(lo + CH, E);
    for (int i = lo + threadIdx.x; i < hi; i += blockDim.x) {
        int k = key[i];
        int pos = atomicAdd(&h[k >> 9], 1);
        P[pos] = ((k & 511) << PAYBITS) | pay[i];
    }
}

__launch_bounds__(512)
__global__ void k_fine2(const int* __restrict__ cStartIn, const int* __restrict__ cStartOut,
                        const int* __restrict__ P_in, const int* __restrict__ P_out,
                        int* __restrict__ start_in, int* __restrict__ start_out,
                        int* __restrict__ csr_in, int* __restrict__ csr_out, int N) {
    int dir = blockIdx.y;
    const int* cStart = dir ? cStartOut : cStartIn;
    const int* P      = dir ? P_out     : P_in;
    int* start        = dir ? start_out : start_in;
    int* csr          = dir ? csr_out   : csr_in;
    __shared__ int cnt[512], scn[512];
    int b = blockIdx.x;
    int lo = cStart[b], hi = cStart[b + 1];
    cnt[threadIdx.x] = 0;
    __syncthreads();
    for (int i = lo + threadIdx.x; i < hi; i += 512)
        atomicAdd(&cnt[P[i] >> PAYBITS], 1);
    __syncthreads();
    int own = cnt[threadIdx.x];
    scn[threadIdx.x] = own;
    __syncthreads();
    for (int off = 1; off < 512; off <<= 1) {
        int t = (threadIdx.x >= off) ? scn[threadIdx.x - off] : 0;
        __syncthreads();
        scn[threadIdx.x] += t;
        __syncthreads();
    }
    int base = lo + scn[threadIdx.x] - own;
    int node = (b << 9) + threadIdx.x;
    if (node < N) start[node] = base;
    cnt[threadIdx.x] = base;   // reuse as cursor
    __syncthreads();
    for (int i = lo + threadIdx.x; i < hi; i += 512) {
        int p = P[i];
        int pos = atomicAdd(&cnt[p >> PAYBITS], 1);
        csr[pos] = p & PAYMASK;
    }
}

// ==== per-node prep (norms, masses, dHdP) + pair-packed fp16 weights =======
__global__ void k_prep(const float* __restrict__ q, const float* __restrict__ p,
                       const float* __restrict__ M,
                       const float* __restrict__ W1, const float* __restrict__ W2,
                       unsigned* __restrict__ Fp, unsigned* __restrict__ Bp,
                       int* __restrict__ start_in, int* __restrict__ start_out,
                       float* __restrict__ a, float* __restrict__ b,
                       __half2* __restrict__ hm, __half* __restrict__ qn,
                       float* __restrict__ out, int N, int E) {
    int t = blockIdx.x * blockDim.x + threadIdx.x;
    if (t == 0) { start_in[N] = E; start_out[N] = E; }
    if (t < 128) {                       // one thread packs one (j0, j0+16) pair
        int ci = t >> 4, l16 = t & 15;
        int j0 = ci * 32 + l16, j1 = j0 + 16;
        unsigned* F = Fp + t * FPITCH;
        unsigned* B = Bp + t * BPITCH;
#pragma unroll
        for (int k = 0; k < 4; k++) {
            unsigned c0 = pk2(W1[(2 * k) * HH + j0], W1[(2 * k + 1) * HH + j0]);
            unsigned c1 = pk2(W1[(2 * k) * HH + j1], W1[(2 * k + 1) * HH + j1]);
            F[k] = c0; F[4 + k] = c1; B[k] = c0; B[4 + k] = c1;
        }
#pragma unroll
        for (int k = 0; k < 8; k++)
            F[8 + k] = pk2(W2[j0 * DD + k], W2[j1 * DD + k]);
#pragma unroll
        for (int kk = 0; kk < 4; kk++) {
            B[8 + kk]  = pk2(W2[j0 * DD + 2 * kk], W2[j0 * DD + 2 * kk + 1]);
            B[12 + kk] = pk2(W2[j1 * DD + 2 * kk], W2[j1 * DD + 2 * kk + 1]);
        }
#pragma unroll
        for (int d = 0; d < 8; d++)
            B[16 + d] = pk2(W1[d * HH + j0], W1[d * HH + j1]);
        B[24] = 0; B[25] = 0; B[26] = 0; B[27] = 0;
    }
    int v = t;
    if (v >= N) return;
    int ei1 = (v + 1 < N) ? start_in[v + 1]  : E;
    int eo1 = (v + 1 < N) ? start_out[v + 1] : E;
    float din  = (float)(ei1 - start_in[v]);
    float dout = (float)(eo1 - start_out[v]);
    float av = 1.0f / sqrtf(dout > 0.f ? dout : 1.f);   // norm_src
    float bv = 1.0f / sqrtf(din  > 0.f ? din  : 1.f);   // norm_dst
    a[v] = av; b[v] = bv;
#pragma unroll
    for (int d = 0; d < DD; d++) {
        float m = M[(size_t)v * DD * DD + d * (DD + 1)];
        __half2 hmv;
        hmv.x = __float2half(0.f);
        hmv.y = __float2half(m);
        hm[(size_t)v * DD + d] = hmv;
        qn[(size_t)v * DD + d] = __float2half(av * q[(size_t)v * DD + d]);
        out[(size_t)v * 2 * DD + DD + d] = p[(size_t)v * DD + d] / m;  // dHdP
    }
}

// ------------------- record unpack/accumulate helpers -----------------------
static __device__ __forceinline__
void acc_h8(uint4 r, float acc[8]) {
    float2 f;
    f = __half22float2(*(__half2*)&r.x); acc[0] += f.x; acc[1] += f.y;
    f = __half22float2(*(__half2*)&r.y); acc[2] += f.x; acc[3] += f.y;
    f = __half22float2(*(__half2*)&r.z); acc[4] += f.x; acc[5] += f.y;
    f = __half22float2(*(__half2*)&r.w); acc[6] += f.x; acc[7] += f.y;
}

static __device__ __forceinline__
void unpack_hm(uint4 r0, uint4 r1, float h[8], float m[8]) {
    float2 f;
    f = __half22float2(*(__half2*)&r0.x); h[0] = f.x; m[0] = f.y;
    f = __half22float2(*(__half2*)&r0.y); h[1] = f.x; m[1] = f.y;
    f = __half22float2(*(__half2*)&r0.z); h[2] = f.x; m[2] = f.y;
    f = __half22float2(*(__half2*)&r0.w); h[3] = f.x; m[3] = f.y;
    f = __half22float2(*(__half2*)&r1.x); h[4] = f.x; m[4] = f.y;
    f = __half22float2(*(__half2*)&r1.y); h[5] = f.x; m[5] = f.y;
    f = __half22float2(*(__half2*)&r1.z); h[6] = f.x; m[6] = f.y;
    f = __half22float2(*(__half2*)&r1.w); h[7] = f.x; m[7] = f.y;
}

// gather full half8 records over csr range into acc[8]
static __device__ __forceinline__
void gather_h8(const int* __restrict__ csr, const __half* __restrict__ x,
               int e, int e1, float acc[8]) {
    for (; e + 3 < e1; e += 4) {
        int u0 = csr[e], u1 = csr[e + 1], u2 = csr[e + 2], u3 = csr[e + 3];
        uint4 r0 = *(const uint4*)(x + (size_t)u0 * DD);
        uint4 r1 = *(const uint4*)(x + (size_t)u1 * DD);
        uint4 r2 = *(const uint4*)(x + (size_t)u2 * DD);
        uint4 r3 = *(const uint4*)(x + (size_t)u3 * DD);
        acc_h8(r0, acc); acc_h8(r1, acc); acc_h8(r2, acc); acc_h8(r3, acc);
    }
    for (; e < e1; e++) {
        uint4 r = *(const uint4*)(x + (size_t)csr[e] * DD);
        acc_h8(r, acc);
    }
}

// ===== FUSED: agg1 = AggIn(qn) + MLP forward, 16 lanes/node, pair-dot2 =====
__launch_bounds__(256)
__global__ void k_agg_mlp_fwd(const int* __restrict__ start, const int* __restrict__ csr,
                              const __half* __restrict__ qn,
                              const float* __restrict__ a, const float* __restrict__ b,
                              const unsigned* __restrict__ Fp, const float* __restrict__ b1,
                              float* __restrict__ agg1, __half* __restrict__ ya, int N) {
    __shared__ unsigned sF[128 * FPITCH];   // 10 KB
    __shared__ float sb1[HH];
    for (int i = threadIdx.x; i < 128 * FPITCH; i += 256) sF[i] = Fp[i];
    for (int i = threadIdx.x; i < HH; i += 256) sb1[i] = b1[i];
    __syncthreads();
    int t = blockIdx.x * 256 + threadIdx.x;
    int v = t >> 4, l16 = t & 15, sub = (t >> 3) & 1, d = t & 7;
    if (v >= N) return;
    int e0 = start[v], e1 = start[v + 1];
    float ag[DD] = {0.f, 0.f, 0.f, 0.f, 0.f, 0.f, 0.f, 0.f};
    for (int e = e0 + l16; e < e1; e += 16) {
        uint4 r = *(const uint4*)(qn + (size_t)csr[e] * DD);
        acc_h8(r, ag);
    }
    red16(ag);
    if (l16 < 2) {
        float4 val = l16 ? make_float4(ag[4], ag[5], ag[6], ag[7])
                         : make_float4(ag[0], ag[1], ag[2], ag[3]);
        ((float4*)(agg1 + (size_t)v * DD))[l16] = val;
    }
    float bv = b[v];
    h2f zh[4];
#pragma unroll
    for (int k = 0; k < 4; k++) zh[k] = pkh(bv * ag[2 * k], bv * ag[2 * k + 1]);
    float acc[DD] = {0.f, 0.f, 0.f, 0.f, 0.f, 0.f, 0.f, 0.f};
#pragma unroll
    for (int ci = 0; ci < 8; ci++) {
        int pid = ci * 16 + l16;
        const uint4* pw = (const uint4*)(sF + pid * FPITCH);
        uint4 w1a = pw[0], w1b = pw[1], w2p0 = pw[2], w2p1 = pw[3];
        int j0 = ci * 32 + l16;
        float u0 = sb1[j0], u1 = sb1[j0 + 16];
        u0 = dot2u(w1a.x, zh[0], u0); u0 = dot2u(w1a.y, zh[1], u0);
        u0 = dot2u(w1a.z, zh[2], u0); u0 = dot2u(w1a.w, zh[3], u0);
        u1 = dot2u(w1b.x, zh[0], u1); u1 = dot2u(w1b.y, zh[1], u1);
        u1 = dot2u(w1b.z, zh[2], u1); u1 = dot2u(w1b.w, zh[3], u1);
        h2f hh = pkh(fmaxf(u0, 0.f), fmaxf(u1, 0.f));
        acc[0] = dot2u(w2p0.x, hh, acc[0]); acc[1] = dot2u(w2p0.y, hh, acc[1]);
        acc[2] = dot2u(w2p0.z, hh, acc[2]); acc[3] = dot2u(w2p0.w, hh, acc[3]);
        acc[4] = dot2u(w2p1.x, hh, acc[4]); acc[5] = dot2u(w2p1.y, hh, acc[5]);
        acc[6] = dot2u(w2p1.z, hh, acc[6]); acc[7] = dot2u(w2p1.w, hh, acc[7]);
    }
    red16(acc);
    float yl = acc[0];
#pragma unroll
    for (int k = 1; k < DD; k++) yl = (d == k) ? acc[k] : yl;
    if (!sub) ya[(size_t)v * DD + d] = __float2half(a[v] * yl);
}

// h = b*AggIn(ya) + b2 + q  -> .x halves of hm records; 8 thr/node
__launch_bounds__(256)
__global__ void k_h_node(const int* __restrict__ start, const int* __restrict__ csr,
                         const __half* __restrict__ ya, const float* __restrict__ b,
                         const float* __restrict__ q, const float* __restrict__ b2,
                         __half2* __restrict__ hm, int N) {
    int t = blockIdx.x * 256 + threadIdx.x;
    int v = t >> 3, sub = t & 7;
    if (v >= N) return;
    int e0 = start[v], e1 = start[v + 1], len = e1 - e0;
    int lo = e0 + (len * sub) / 8, hi = e0 + (len * (sub + 1)) / 8;
    float acc[8] = {0.f, 0.f, 0.f, 0.f, 0.f, 0.f, 0.f, 0.f};
    gather_h8(csr, ya, lo, hi, acc);
    red8(acc);
    if (sub == 0) {
        float bv = b[v];
        const float4* qp = (const float4*)(q + (size_t)v * DD);
        float4 q0 = qp[0], q1 = qp[1];
        float hq[8] = {q0.x, q0.y, q0.z, q0.w, q1.x, q1.y, q1.z, q1.w};
        __half2* hp = hm + (size_t)v * DD;
#pragma unroll
        for (int k = 0; k < DD; k++) {
            float hval = fmaf(bv, acc[k], b2[k] + hq[k]);
            __half2 cur = hp[k];
            cur.x = __float2half(hval);
            hp[k] = cur;
        }
    }
}

// gravity gradient: 8 threads/node (dir x quarter-range)
__launch_bounds__(256)
__global__ void k_gh4(const int* __restrict__ start_in, const int* __restrict__ csr_in,
                      const int* __restrict__ start_out, const int* __restrict__ csr_out,
                      const __half2* __restrict__ hm,
                      const float* __restrict__ b, const float* __restrict__ grav,
                      float* __restrict__ gh, __half* __restrict__ bgh, int N) {
    int t = blockIdx.x * 256 + threadIdx.x;
    int v = t >> 3, sub = t & 7, dir = sub >> 2, qr = sub & 3;
    if (v >= N) return;
    const uint4* srec = (const uint4*)(hm + (size_t)v * DD);
    uint4 s0 = srec[0], s1 = srec[1];
    float hv[8], mv[8];
    unpack_hm(s0, s1, hv, mv);
    const int* start = dir ? start_out : start_in;
    const int* csr   = dir ? csr_out   : csr_in;
    int e0 = start[v], e1 = start[v + 1], len = e1 - e0;
    int e  = e0 + (len * qr) / 4;
    int hi = e0 + (len * (qr + 1)) / 4;
    float coef = -0.5f * grav[0];
    float acc[8] = {0.f, 0.f, 0.f, 0.f, 0.f, 0.f, 0.f, 0.f};
    for (; e + 1 < hi; e += 2) {
        int u0 = csr[e], u1 = csr[e + 1];
        const uint4* r0p = (const uint4*)(hm + (size_t)u0 * DD);
        const uint4* r1p = (const uint4*)(hm + (size_t)u1 * DD);
        uint4 x0 = r0p[0], x1 = r0p[1], y0 = r1p[0], y1 = r1p[1];
        float hu0[8], mu0[8], hu1[8], mu1[8];
        unpack_hm(x0, x1, hu0, mu0);
        unpack_hm(y0, y1, hu1, mu1);
        float d0[8], d1[8];
        float e20 = 0.f, S0 = 0.f, e21 = 0.f, S1 = 0.f;
#pragma unroll
        for (int k = 0; k < 8; k++) {
            d0[k] = hv[k] - hu0[k];
            d1[k] = hv[k] - hu1[k];
            e20 = fmaf(d0[k], d0[k], e20);
            e21 = fmaf(d1[k], d1[k], e21);
            S0 = fmaf(mv[k], mu0[k], S0);
            S1 = fmaf(mv[k], mu1[k], S1);
        }
        float r0 = rsqrtf(e20), r1 = rsqrtf(e21);
        float c0 = coef * S0 * r0 * r0 * r0;
        float c1 = coef * S1 * r1 * r1 * r1;
#pragma unroll
        for (int k = 0; k < 8; k++)
            acc[k] = fmaf(c0, d0[k], fmaf(c1, d1[k], acc[k]));
    }
    if (e < hi) {
        int u = csr[e];
        const uint4* rp = (const uint4*)(hm + (size_t)u * DD);
        uint4 x0 = rp[0], x1 = rp[1];
        float hu[8], mu[8];
        unpack_hm(x0, x1, hu, mu);
        float df[8];
        float e2 = 0.f, S = 0.f;
#pragma unroll
        for (int k = 0; k < 8; k++) {
            df[k] = hv[k] - hu[k];
            e2 = fmaf(df[k], df[k], e2);
            S = fmaf(mv[k], mu[k], S);
        }
        float r = rsqrtf(e2);
        float c = coef * S * r * r * r;
#pragma unroll
        for (int k = 0; k < 8; k++) acc[k] = fmaf(c, df[k], acc[k]);
    }
    red8(acc);   // combine the 8 subset threads via DPP
    if (sub == 0) {
        float4* gp = (float4*)(gh + (size_t)v * DD);
        gp[0] = make_float4(acc[0], acc[1], acc[2], acc[3]);
        gp[1] = make_float4(acc[4], acc[5], acc[6], acc[7]);
        float bv = b[v];
        __half2* bp = (__half2*)(bgh + (size_t)v * DD);
        bp[0] = __floats2half2_rn(bv * acc[0], bv * acc[1]);
        bp[1] = __floats2half2_rn(bv * acc[2], bv * acc[3]);
        bp[2] = __floats2half2_rn(bv * acc[4], bv * acc[5]);
        bp[3] = __floats2half2_rn(bv * acc[6], bv * acc[7]);
    }
}

// ===== FUSED: gq = AggOut(bgh) + MLP backward, 16 lanes/node, pair-dot2 =====
__launch_bounds__(256)
__global__ void k_bgh_mlp_bwd(const int* __restrict__ start, const int* __restrict__ csr,
                              const __half* __restrict__ bgh,
                              const float* __restrict__ agg1,
                              const float* __restrict__ a, const float* __restrict__ b,
                              const unsigned* __restrict__ Bp, const float* __restrict__ b1,
                              __half* __restrict__ gz1b, int N) {
    __shared__ unsigned sB[128 * BPITCH];   // 14 KB
    __shared__ float sb1[HH];
    for (int i = threadIdx.x; i < 128 * BPITCH; i += 256) sB[i] = Bp[i];
    for (int i = threadIdx.x; i < HH; i += 256) sb1[i] = b1[i];
    __syncthreads();
    int t = blockIdx.x * 256 + threadIdx.x;
    int v = t >> 4, l16 = t & 15, sub = (t >> 3) & 1, d = t & 7;
    if (v >= N) return;
    int e0 = start[v], e1 = start[v + 1];
    float gq[DD] = {0.f, 0.f, 0.f, 0.f, 0.f, 0.f, 0.f, 0.f};
    for (int e = e0 + l16; e < e1; e += 16) {
        uint4 r = *(const uint4*)(bgh + (size_t)csr[e] * DD);
        acc_h8(r, gq);
    }
    red16(gq);
    float bv = b[v], av = a[v];
    const float4* ap = (const float4*)(agg1 + (size_t)v * DD);
    float4 a0 = ap[0], a1 = ap[1];
    h2f zh[4], gqh[4];
    zh[0] = pkh(bv * a0.x, bv * a0.y); zh[1] = pkh(bv * a0.z, bv * a0.w);
    zh[2] = pkh(bv * a1.x, bv * a1.y); zh[3] = pkh(bv * a1.z, bv * a1.w);
#pragma unroll
    for (int k = 0; k < 4; k++) gqh[k] = pkh(gq[2 * k], gq[2 * k + 1]);
    float gz[DD] = {0.f, 0.f, 0.f, 0.f, 0.f, 0.f, 0.f, 0.f};
#pragma unroll
    for (int ci = 0; ci < 8; ci++) {
        int pid = ci * 16 + l16;
        const uint4* pw = (const uint4*)(sB + pid * BPITCH);
        uint4 w1a = pw[0], w1b = pw[1], w2r0 = pw[2], w2r1 = pw[3];
        uint4 g0p = pw[4], g1p = pw[5];
        int j0 = ci * 32 + l16;
        float u0 = sb1[j0], u1 = sb1[j0 + 16];
        u0 = dot2u(w1a.x, zh[0], u0); u0 = dot2u(w1a.y, zh[1], u0);
        u0 = dot2u(w1a.z, zh[2], u0); u0 = dot2u(w1a.w, zh[3], u0);
        u1 = dot2u(w1b.x, zh[0], u1); u1 = dot2u(w1b.y, zh[1], u1);
        u1 = dot2u(w1b.z, zh[2], u1); u1 = dot2u(w1b.w, zh[3], u1);
        float ga0 = dot2u(w2r0.x, gqh[0], 0.f);
        ga0 = dot2u(w2r0.y, gqh[1], ga0);
        ga0 = dot2u(w2r0.z, gqh[2], ga0);
        ga0 = dot2u(w2r0.w, gqh[3], ga0);
        float ga1 = dot2u(w2r1.x, gqh[0], 0.f);
        ga1 = dot2u(w2r1.y, gqh[1], ga1);
        ga1 = dot2u(w2r1.z, gqh[2], ga1);
        ga1 = dot2u(w2r1.w, gqh[3], ga1);
        float g0 = (u0 > 0.f) ? av * ga0 : 0.f;
        float g1 = (u1 > 0.f) ? av * ga1 : 0.f;
        h2f gg = pkh(g0, g1);
        gz[0] = dot2u(g0p.x, gg, gz[0]); gz[1] = dot2u(g0p.y, gg, gz[1]);
        gz[2] = dot2u(g0p.z, gg, gz[2]); gz[3] = dot2u(g0p.w, gg, gz[3]);
        gz[4] = dot2u(g1p.x, gg, gz[4]); gz[5] = dot2u(g1p.y, gg, gz[5]);
        gz[6] = dot2u(g1p.z, gg, gz[6]); gz[7] = dot2u(g1p.w, gg, gz[7]);
    }
    red16(gz);
    float out_l = gz[0];
#pragma unroll
    for (int k = 1; k < DD; k++) out_l = (d == k) ? gz[k] : out_l;
    if (!sub) gz1b[(size_t)v * DD + d] = __float2half(bv * out_l);
}

// out[:, :D] = gh + a * AggOut(gz1b); 8 thr/node
__launch_bounds__(256)
__global__ void k_out_node(const int* __restrict__ start, const int* __restrict__ csr,
                           const __half* __restrict__ gz1b, const float* __restrict__ gh,
                           const float* __restrict__ a, float* __restrict__ out, int N) {
    int t = blockIdx.x * 256 + threadIdx.x;
    int v = t >> 3, sub = t & 7;
    if (v >= N) return;
    int e0 = start[v], e1 = start[v + 1], len = e1 - e0;
    int lo = e0 + (len * sub) / 8, hi = e0 + (len * (sub + 1)) / 8;
    float acc[8] = {0.f, 0.f, 0.f, 0.f, 0.f, 0.f, 0.f, 0.f};
    gather_h8(csr, gz1b, lo, hi, acc);
    red8(acc);
    if (sub == 0) {
        float av = a[v];
        const float4* gp = (const float4*)(gh + (size_t)v * DD);
        float4 g0 = gp[0], g1 = gp[1];
        float4* op = (float4*)(out + (size_t)v * 2 * DD);
        op[0] = make_float4(fmaf(av, acc[0], g0.x), fmaf(av, acc[1], g0.y),
                            fmaf(av, acc[2], g0.z), fmaf(av, acc[3], g0.w));
        op[1] = make_float4(fmaf(av, acc[4], g1.x), fmaf(av, acc[5], g1.y),
                            fmaf(av, acc[6], g1.z), fmaf(av, acc[7], g1.w));
    }
}

// ============================== launch =====================================

extern "C" void kernel_launch(void* const* d_in, const int* in_sizes, int n_in,
                              void* d_out, int out_size, void* d_ws, size_t ws_size,
                              hipStream_t stream) {
    const float* q    = (const float*)d_in[0];
    const float* p    = (const float*)d_in[1];
    const float* M    = (const float*)d_in[2];
    const int*   src  = (const int*)d_in[3];
    const int*   dst  = (const int*)d_in[4];
    const float* W1   = (const float*)d_in[5];
    const float* b1   = (const float*)d_in[6];
    const float* W2   = (const float*)d_in[7];
    const float* b2   = (const float*)d_in[8];
    const float* grav = (const float*)d_in[9];
    float* out = (float*)d_out;

    int N = in_sizes[0] / DD;
    int E = in_sizes[3];
    size_t n = (size_t)N;
    int NB = (N + 511) >> 9;
    int NC = (E + CH - 1) / CH;

    // ---- data region (46N 4-byte words) ----
    float*   ws   = (float*)d_ws;
    float*   a_   = ws;             // N
    float*   b_   = ws + n;         // N
    __half*  qn   = (__half*)(ws + 2 * n);    // 8N half (4N words; region keeps 8N)
    float*   agg1 = ws + 10 * n;    // 8N f32 (live through bwd)
    float*   gh   = ws + 18 * n;    // 8N f32
    __half2* hm   = (__half2*)(ws + 26 * n);  // 8N half2 (8N words)
    __half*  ya   = (__half*)(ws + 34 * n);   // 8N half (4N words)
    __half*  bgh  = (__half*)(ws + 38 * n);   // 8N half (4N words)
    __half*  gz1b = (__half*)(ws + 42 * n);   // 8N half (4N words)

    // ---- int region ----
    int* iw        = (int*)(ws + 46 * n);
    int* csr_in    = iw;                       // E
    int* csr_out   = iw + (size_t)E;           // E
    int* start_in  = iw + 2 * (size_t)E;       // N+1
    int* start_out = start_in + n + 1;         // N+1
    int* cStartIn  = start_out + n + 1;        // NB+1
    int* cStartOut = cStartIn + NB + 1;        // NB+1
    int* binTotIn  = cStartOut + NB + 1;       // 256
    int* binTotOut = binTotIn + 256;           // 256
    int* binStartIn  = binTotOut + 256;        // 256
    int* binStartOut = binStartIn + 256;       // 256
    int* iwEnd     = binStartOut + 256;
    unsigned* Fp   = (unsigned*)iwEnd;         // 128*FPITCH = 2560 uints
    unsigned* Bp   = Fp + 128 * FPITCH;        // 128*BPITCH = 3584 uints
    int* cHistIn   = (int*)(Bp + 128 * BPITCH);  // NC*256 (becomes chunk-local bases)
    int* cHistOut  = cHistIn + (size_t)NC * 256; // NC*256
    int* intAfter  = cHistOut + (size_t)NC * 256;
    // partition scratch: both dirs alias the data region (dead during build)
    int* P_in  = (E <= 16 * (long long)n) ? (int*)ws            : intAfter;
    int* P_out = (E <= 16 * (long long)n) ? (int*)(ws + 16 * n) : intAfter + E;

    const int tb = 256;
    int gbN  = (N + tb - 1) / tb;
    int gb8  = (int)((8 * n + tb - 1) / tb);   // 8 threads/node
    int gb16 = (int)((16 * n + tb - 1) / tb);  // 16 lanes/node

    // CSR build
    k_coarse  <<<NC, tb, 0, stream>>>(src, dst, cHistIn, cHistOut, E);
    k_cscan1  <<<dim3(256, 2), tb, 0, stream>>>(cHistIn, cHistOut,
                                                binTotIn, binTotOut, NC);
    k_cscan2  <<<1, 256, 0, stream>>>(binTotIn, binTotOut, binStartIn, binStartOut,
                                      cStartIn, cStartOut, NB, E);
    k_part2   <<<dim3(NC, 2), tb, 0, stream>>>(src, dst, cHistIn, cHistOut,
                                               binStartIn, binStartOut,
                                               P_in, P_out, E);
    k_fine2   <<<dim3(NB, 2), 512, 0, stream>>>(cStartIn, cStartOut, P_in, P_out,
                                                start_in, start_out, csr_in, csr_out, N);
    k_prep    <<<gbN, tb, 0, stream>>>(q, p, M, W1, W2, Fp, Bp, start_in, start_out,
                                       a_, b_, hm, qn, out, N, E);

    // forward: [agg1 = AggIn(a*q)] + [ya = a*(relu((b*agg1)@W1+b1)@W2)] fused
    k_agg_mlp_fwd<<<gb16, tb, 0, stream>>>(start_in, csr_in, qn, a_, b_,
                                           Fp, b1, agg1, ya, N);
    // h = b * AggIn(ya) + b2 + q  -> .x halves of hm
    k_h_node  <<<gb8, tb, 0, stream>>>(start_in, csr_in, ya, b_, q, b2, hm, N);
    // gravity gradient (8 threads/node, full records in-thread)
    k_gh4     <<<gb8, tb, 0, stream>>>(start_in, csr_in, start_out, csr_out,
                                       hm, b_, grav, gh, bgh, N);
    // [gq = AggOut(bgh)] + [gz1b = b*((a*(gq@W2^T)*relu')@W1^T)] fused
    k_bgh_mlp_bwd<<<gb16, tb, 0, stream>>>(start_out, csr_out, bgh, agg1, a_, b_,
                                           Bp, b1, gz1b, N);
    // dHdQ = gh + a * AggOut(gz1b)
    k_out_node<<<gb8, tb, 0, stream>>>(start_out, csr_out, gz1b, gh, a_, out, N);
}

// Round 14
// 285.351 us; speedup vs baseline: 1.3034x; 1.0042x over previous
//
#include <hip/hip_runtime.h>
#include <hip/hip_fp16.h>

#define DD 8
#define HH 256
#define CH 8192          // edges per chunk: 41-edge runs/bin -> full-line scatter writes
#define PAYBITS 17       // N <= 131072
#define PAYMASK 0x1FFFF
#define FPITCH 20        // fwd pair-pack pitch (uints): 80B, 16B-aligned, 2-way banks
#define BPITCH 28        // bwd pair-pack pitch (uints): 112B, 16B-aligned, 2-way banks

// R13: 286.6us (best). R14: eliminate k_cscan2 -- its 256-bin exclusive scan
// of binTot is recomputed in-block by part2 and fine2 (8 LDS-scan iterations,
// parallel across all blocks, ~free). 11 -> 10 dispatches; cStart/binStart
// arrays deleted. binTot crosses a kernel boundary (full visibility).

typedef _Float16 h2f __attribute__((ext_vector_type(2)));

static __device__ __forceinline__ float dot2u(unsigned w, h2f z, float c) {
#if __has_builtin(__builtin_amdgcn_fdot2)
    return __builtin_amdgcn_fdot2(__builtin_bit_cast(h2f, w), z, c, false);
#else
    __half2 h = __builtin_bit_cast(__half2, w);
    float2 f = __half22float2(h);
    return fmaf(f.y, (float)z[1], fmaf(f.x, (float)z[0], c));
#endif
}
static __device__ __forceinline__ h2f pkh(float a, float b) {
    h2f r; r[0] = (_Float16)a; r[1] = (_Float16)b; return r;
}
static __device__ __forceinline__ unsigned pk2(float a, float b) {
    __half2 hh; hh.x = __float2half(a); hh.y = __float2half(b);
    return *(unsigned*)&hh;
}

// ---- DPP lane-group sum (VALU pipe; no LDS round-trips) ----
template <int CTRL>
static __device__ __forceinline__ float dppadd(float x) {
    int y = __builtin_amdgcn_update_dpp(0, __builtin_bit_cast(int, x),
                                        CTRL, 0xF, 0xF, true);
    return x + __builtin_bit_cast(float, y);
}
static __device__ __forceinline__ void red16(float a[8]) {
#pragma unroll
    for (int k = 0; k < 8; k++) a[k] = dppadd<0xB1>(a[k]);   // xor1
#pragma unroll
    for (int k = 0; k < 8; k++) a[k] = dppadd<0x4E>(a[k]);   // xor2
#pragma unroll
    for (int k = 0; k < 8; k++) a[k] = dppadd<0x141>(a[k]);  // row_half_mirror
#pragma unroll
    for (int k = 0; k < 8; k++) a[k] = dppadd<0x140>(a[k]);  // row_mirror
}
// sum over aligned 8-lane group (result in all 8 lanes)
static __device__ __forceinline__ void red8(float a[8]) {
#pragma unroll
    for (int k = 0; k < 8; k++) a[k] = dppadd<0xB1>(a[k]);
#pragma unroll
    for (int k = 0; k < 8; k++) a[k] = dppadd<0x4E>(a[k]);
#pragma unroll
    for (int k = 0; k < 8; k++) a[k] = dppadd<0x141>(a[k]);
}

// ============================ CSR construction ==============================

// per-chunk 256-bin histograms for both dirs -> global (coalesced)
__global__ void k_coarse(const int* __restrict__ src, const int* __restrict__ dst,
                         int* __restrict__ cHistIn, int* __restrict__ cHistOut,
                         int E) {
    __shared__ int hIn[256], hOut[256];
    hIn[threadIdx.x] = 0; hOut[threadIdx.x] = 0;
    __syncthreads();
    int lo = blockIdx.x * CH;
    int hi = min(lo + CH, E);
    for (int i = lo + threadIdx.x; i < hi; i += blockDim.x) {
        atomicAdd(&hIn[dst[i] >> 9], 1);
        atomicAdd(&hOut[src[i] >> 9], 1);
    }
    __syncthreads();
    cHistIn [blockIdx.x * 256 + threadIdx.x] = hIn[threadIdx.x];
    cHistOut[blockIdx.x * 256 + threadIdx.x] = hOut[threadIdx.x];
}

// one block per (bin, dir) -- parallel scan over chunks for that bin.
// cH[c][bin] <- exclusive chunk-local offset; binTot[bin] <- bin total.
__global__ void k_cscan1(int* __restrict__ cHistIn, int* __restrict__ cHistOut,
                         int* __restrict__ binTotIn, int* __restrict__ binTotOut,
                         int NC) {
    int bin = blockIdx.x;
    int* cH = blockIdx.y ? cHistOut : cHistIn;
    int* bT = blockIdx.y ? binTotOut : binTotIn;
    __shared__ int s[256];
    int tid = threadIdx.x;
    int carry = 0;
    for (int base = 0; base < NC; base += 256) {
        int c = base + tid;
        int val = (c < NC) ? cH[(size_t)c * 256 + bin] : 0;
        s[tid] = val;
        __syncthreads();
        for (int off = 1; off < 256; off <<= 1) {
            int t = (tid >= off) ? s[tid - off] : 0;
            __syncthreads();
            s[tid] += t;
            __syncthreads();
        }
        int excl = s[tid] - val + carry;
        if (c < NC) cH[(size_t)c * 256 + bin] = excl;
        carry += s[255];
        __syncthreads();
    }
    if (tid == 0) bT[bin] = carry;
}

// single scatter pass; cursors = chunk-local offset + binStart (scanned in-block)
__global__ void k_part2(const int* __restrict__ src, const int* __restrict__ dst,
                        const int* __restrict__ cBaseIn, const int* __restrict__ cBaseOut,
                        const int* __restrict__ binTotIn, const int* __restrict__ binTotOut,
                        int* __restrict__ P_in, int* __restrict__ P_out, int E) {
    int dir = blockIdx.y;
    const int* key   = dir ? src : dst;
    const int* pay   = dir ? dst : src;
    const int* cBase = dir ? cBaseOut : cBaseIn;
    const int* bT    = dir ? binTotOut : binTotIn;
    int* P           = dir ? P_out    : P_in;
    __shared__ int s[256], h[256];
    int tid = threadIdx.x;
    int tot = bT[tid];
    s[tid] = tot;
    __syncthreads();
    for (int off = 1; off < 256; off <<= 1) {
        int t = (tid >= off) ? s[tid - off] : 0;
        __syncthreads();
        s[tid] += t;
        __syncthreads();
    }
    h[tid] = cBase[blockIdx.x * 256 + tid] + (s[tid] - tot);   // + binStart
    __syncthreads();
    int lo = blockIdx.x * CH;
    int hi = min(lo + CH, E);
    for (int i = lo + tid; i < hi; i += blockDim.x) {
        int k = key[i];
        int pos = atomicAdd(&h[k >> 9], 1);
        P[pos] = ((k & 511) << PAYBITS) | pay[i];
    }
}

__launch_bounds__(512)
__global__ void k_fine2(const int* __restrict__ binTotIn, const int* __restrict__ binTotOut,
                        const int* __restrict__ P_in, const int* __restrict__ P_out,
                        int* __restrict__ start_in, int* __restrict__ start_out,
                        int* __restrict__ csr_in, int* __restrict__ csr_out, int N) {
    int dir = blockIdx.y;
    const int* bT = dir ? binTotOut : binTotIn;
    const int* P  = dir ? P_out     : P_in;
    int* start    = dir ? start_out : start_in;
    int* csr      = dir ? csr_out   : csr_in;
    __shared__ int cnt[512], scn[512];
    __shared__ int s[256];
    __shared__ int sLo, sHi;
    int tid = threadIdx.x;
    int b = blockIdx.x;
    // in-block 256-bin scan of binTot -> this bin's P range [sLo, sHi)
    int v = (tid < 256) ? bT[tid] : 0;
    if (tid < 256) s[tid] = v;
    __syncthreads();
    for (int off = 1; off < 256; off <<= 1) {
        int t = (tid < 256 && tid >= off) ? s[tid - off] : 0;
        __syncthreads();
        if (tid < 256) s[tid] += t;
        __syncthreads();
    }
    if (tid == 0) {
        int incl = s[b];
        sLo = incl - bT[b];
        sHi = incl;
    }
    __syncthreads();
    int lo = sLo, hi = sHi;
    cnt[tid] = 0;
    __syncthreads();
    for (int i = lo + tid; i < hi; i += 512)
        atomicAdd(&cnt[P[i] >> PAYBITS], 1);
    __syncthreads();
    int own = cnt[tid];
    scn[tid] = own;
    __syncthreads();
    for (int off = 1; off < 512; off <<= 1) {
        int t = (tid >= off) ? scn[tid - off] : 0;
        __syncthreads();
        scn[tid] += t;
        __syncthreads();
    }
    int base = lo + scn[tid] - own;
    int node = (b << 9) + tid;
    if (node < N) start[node] = base;
    cnt[tid] = base;   // reuse as cursor
    __syncthreads();
    for (int i = lo + tid; i < hi; i += 512) {
        int p = P[i];
        int pos = atomicAdd(&cnt[p >> PAYBITS], 1);
        csr[pos] = p & PAYMASK;
    }
}

// ==== per-node prep (norms, masses, dHdP) + pair-packed fp16 weights =======
__global__ void k_prep(const float* __restrict__ q, const float* __restrict__ p,
                       const float* __restrict__ M,
                       const float* __restrict__ W1, const float* __restrict__ W2,
                       unsigned* __restrict__ Fp, unsigned* __restrict__ Bp,
                       int* __restrict__ start_in, int* __restrict__ start_out,
                       float* __restrict__ a, float* __restrict__ b,
                       __half2* __restrict__ hm, __half* __restrict__ qn,
                       float* __restrict__ out, int N, int E) {
    int t = blockIdx.x * blockDim.x + threadIdx.x;
    if (t == 0) { start_in[N] = E; start_out[N] = E; }
    if (t < 128) {                       // one thread packs one (j0, j0+16) pair
        int ci = t >> 4, l16 = t & 15;
        int j0 = ci * 32 + l16, j1 = j0 + 16;
        unsigned* F = Fp + t * FPITCH;
        unsigned* B = Bp + t * BPITCH;
#pragma unroll
        for (int k = 0; k < 4; k++) {
            unsigned c0 = pk2(W1[(2 * k) * HH + j0], W1[(2 * k + 1) * HH + j0]);
            unsigned c1 = pk2(W1[(2 * k) * HH + j1], W1[(2 * k + 1) * HH + j1]);
            F[k] = c0; F[4 + k] = c1; B[k] = c0; B[4 + k] = c1;
        }
#pragma unroll
        for (int k = 0; k < 8; k++)
            F[8 + k] = pk2(W2[j0 * DD + k], W2[j1 * DD + k]);
#pragma unroll
        for (int kk = 0; kk < 4; kk++) {
            B[8 + kk]  = pk2(W2[j0 * DD + 2 * kk], W2[j0 * DD + 2 * kk + 1]);
            B[12 + kk] = pk2(W2[j1 * DD + 2 * kk], W2[j1 * DD + 2 * kk + 1]);
        }
#pragma unroll
        for (int d = 0; d < 8; d++)
            B[16 + d] = pk2(W1[d * HH + j0], W1[d * HH + j1]);
        B[24] = 0; B[25] = 0; B[26] = 0; B[27] = 0;
    }
    int v = t;
    if (v >= N) return;
    int ei1 = (v + 1 < N) ? start_in[v + 1]  : E;
    int eo1 = (v + 1 < N) ? start_out[v + 1] : E;
    float din  = (float)(ei1 - start_in[v]);
    float dout = (float)(eo1 - start_out[v]);
    float av = 1.0f / sqrtf(dout > 0.f ? dout : 1.f);   // norm_src
    float bv = 1.0f / sqrtf(din  > 0.f ? din  : 1.f);   // norm_dst
    a[v] = av; b[v] = bv;
#pragma unroll
    for (int d = 0; d < DD; d++) {
        float m = M[(size_t)v * DD * DD + d * (DD + 1)];
        __half2 hmv;
        hmv.x = __float2half(0.f);
        hmv.y = __float2half(m);
        hm[(size_t)v * DD + d] = hmv;
        qn[(size_t)v * DD + d] = __float2half(av * q[(size_t)v * DD + d]);
        out[(size_t)v * 2 * DD + DD + d] = p[(size_t)v * DD + d] / m;  // dHdP
    }
}

// ------------------- record unpack/accumulate helpers -----------------------
static __device__ __forceinline__
void acc_h8(uint4 r, float acc[8]) {
    float2 f;
    f = __half22float2(*(__half2*)&r.x); acc[0] += f.x; acc[1] += f.y;
    f = __half22float2(*(__half2*)&r.y); acc[2] += f.x; acc[3] += f.y;
    f = __half22float2(*(__half2*)&r.z); acc[4] += f.x; acc[5] += f.y;
    f = __half22float2(*(__half2*)&r.w); acc[6] += f.x; acc[7] += f.y;
}

static __device__ __forceinline__
void unpack_hm(uint4 r0, uint4 r1, float h[8], float m[8]) {
    float2 f;
    f = __half22float2(*(__half2*)&r0.x); h[0] = f.x; m[0] = f.y;
    f = __half22float2(*(__half2*)&r0.y); h[1] = f.x; m[1] = f.y;
    f = __half22float2(*(__half2*)&r0.z); h[2] = f.x; m[2] = f.y;
    f = __half22float2(*(__half2*)&r0.w); h[3] = f.x; m[3] = f.y;
    f = __half22float2(*(__half2*)&r1.x); h[4] = f.x; m[4] = f.y;
    f = __half22float2(*(__half2*)&r1.y); h[5] = f.x; m[5] = f.y;
    f = __half22float2(*(__half2*)&r1.z); h[6] = f.x; m[6] = f.y;
    f = __half22float2(*(__half2*)&r1.w); h[7] = f.x; m[7] = f.y;
}

// gather full half8 records over csr range into acc[8]
static __device__ __forceinline__
void gather_h8(const int* __restrict__ csr, const __half* __restrict__ x,
               int e, int e1, float acc[8]) {
    for (; e + 3 < e1; e += 4) {
        int u0 = csr[e], u1 = csr[e + 1], u2 = csr[e + 2], u3 = csr[e + 3];
        uint4 r0 = *(const uint4*)(x + (size_t)u0 * DD);
        uint4 r1 = *(const uint4*)(x + (size_t)u1 * DD);
        uint4 r2 = *(const uint4*)(x + (size_t)u2 * DD);
        uint4 r3 = *(const uint4*)(x + (size_t)u3 * DD);
        acc_h8(r0, acc); acc_h8(r1, acc); acc_h8(r2, acc); acc_h8(r3, acc);
    }
    for (; e < e1; e++) {
        uint4 r = *(const uint4*)(x + (size_t)csr[e] * DD);
        acc_h8(r, acc);
    }
}

// ===== FUSED: agg1 = AggIn(qn) + MLP forward, 16 lanes/node, pair-dot2 =====
__launch_bounds__(256)
__global__ void k_agg_mlp_fwd(const int* __restrict__ start, const int* __restrict__ csr,
                              const __half* __restrict__ qn,
                              const float* __restrict__ a, const float* __restrict__ b,
                              const unsigned* __restrict__ Fp, const float* __restrict__ b1,
                              float* __restrict__ agg1, __half* __restrict__ ya, int N) {
    __shared__ unsigned sF[128 * FPITCH];   // 10 KB
    __shared__ float sb1[HH];
    for (int i = threadIdx.x; i < 128 * FPITCH; i += 256) sF[i] = Fp[i];
    for (int i = threadIdx.x; i < HH; i += 256) sb1[i] = b1[i];
    __syncthreads();
    int t = blockIdx.x * 256 + threadIdx.x;
    int v = t >> 4, l16 = t & 15, sub = (t >> 3) & 1, d = t & 7;
    if (v >= N) return;
    int e0 = start[v], e1 = start[v + 1];
    float ag[DD] = {0.f, 0.f, 0.f, 0.f, 0.f, 0.f, 0.f, 0.f};
    for (int e = e0 + l16; e < e1; e += 16) {
        uint4 r = *(const uint4*)(qn + (size_t)csr[e] * DD);
        acc_h8(r, ag);
    }
    red16(ag);
    if (l16 < 2) {
        float4 val = l16 ? make_float4(ag[4], ag[5], ag[6], ag[7])
                         : make_float4(ag[0], ag[1], ag[2], ag[3]);
        ((float4*)(agg1 + (size_t)v * DD))[l16] = val;
    }
    float bv = b[v];
    h2f zh[4];
#pragma unroll
    for (int k = 0; k < 4; k++) zh[k] = pkh(bv * ag[2 * k], bv * ag[2 * k + 1]);
    float acc[DD] = {0.f, 0.f, 0.f, 0.f, 0.f, 0.f, 0.f, 0.f};
#pragma unroll
    for (int ci = 0; ci < 8; ci++) {
        int pid = ci * 16 + l16;
        const uint4* pw = (const uint4*)(sF + pid * FPITCH);
        uint4 w1a = pw[0], w1b = pw[1], w2p0 = pw[2], w2p1 = pw[3];
        int j0 = ci * 32 + l16;
        float u0 = sb1[j0], u1 = sb1[j0 + 16];
        u0 = dot2u(w1a.x, zh[0], u0); u0 = dot2u(w1a.y, zh[1], u0);
        u0 = dot2u(w1a.z, zh[2], u0); u0 = dot2u(w1a.w, zh[3], u0);
        u1 = dot2u(w1b.x, zh[0], u1); u1 = dot2u(w1b.y, zh[1], u1);
        u1 = dot2u(w1b.z, zh[2], u1); u1 = dot2u(w1b.w, zh[3], u1);
        h2f hh = pkh(fmaxf(u0, 0.f), fmaxf(u1, 0.f));
        acc[0] = dot2u(w2p0.x, hh, acc[0]); acc[1] = dot2u(w2p0.y, hh, acc[1]);
        acc[2] = dot2u(w2p0.z, hh, acc[2]); acc[3] = dot2u(w2p0.w, hh, acc[3]);
        acc[4] = dot2u(w2p1.x, hh, acc[4]); acc[5] = dot2u(w2p1.y, hh, acc[5]);
        acc[6] = dot2u(w2p1.z, hh, acc[6]); acc[7] = dot2u(w2p1.w, hh, acc[7]);
    }
    red16(acc);
    float yl = acc[0];
#pragma unroll
    for (int k = 1; k < DD; k++) yl = (d == k) ? acc[k] : yl;
    if (!sub) ya[(size_t)v * DD + d] = __float2half(a[v] * yl);
}

// h = b*AggIn(ya) + b2 + q  -> .x halves of hm records; 8 thr/node
__launch_bounds__(256)
__global__ void k_h_node(const int* __restrict__ start, const int* __restrict__ csr,
                         const __half* __restrict__ ya, const float* __restrict__ b,
                         const float* __restrict__ q, const float* __restrict__ b2,
                         __half2* __restrict__ hm, int N) {
    int t = blockIdx.x * 256 + threadIdx.x;
    int v = t >> 3, sub = t & 7;
    if (v >= N) return;
    int e0 = start[v], e1 = start[v + 1], len = e1 - e0;
    int lo = e0 + (len * sub) / 8, hi = e0 + (len * (sub + 1)) / 8;
    float acc[8] = {0.f, 0.f, 0.f, 0.f, 0.f, 0.f, 0.f, 0.f};
    gather_h8(csr, ya, lo, hi, acc);
    red8(acc);
    if (sub == 0) {
        float bv = b[v];
        const float4* qp = (const float4*)(q + (size_t)v * DD);
        float4 q0 = qp[0], q1 = qp[1];
        float hq[8] = {q0.x, q0.y, q0.z, q0.w, q1.x, q1.y, q1.z, q1.w};
        __half2* hp = hm + (size_t)v * DD;
#pragma unroll
        for (int k = 0; k < DD; k++) {
            float hval = fmaf(bv, acc[k], b2[k] + hq[k]);
            __half2 cur = hp[k];
            cur.x = __float2half(hval);
            hp[k] = cur;
        }
    }
}

// gravity gradient: 8 threads/node (dir x quarter-range)
__launch_bounds__(256)
__global__ void k_gh4(const int* __restrict__ start_in, const int* __restrict__ csr_in,
                      const int* __restrict__ start_out, const int* __restrict__ csr_out,
                      const __half2* __restrict__ hm,
                      const float* __restrict__ b, const float* __restrict__ grav,
                      float* __restrict__ gh, __half* __restrict__ bgh, int N) {
    int t = blockIdx.x * 256 + threadIdx.x;
    int v = t >> 3, sub = t & 7, dir = sub >> 2, qr = sub & 3;
    if (v >= N) return;
    const uint4* srec = (const uint4*)(hm + (size_t)v * DD);
    uint4 s0 = srec[0], s1 = srec[1];
    float hv[8], mv[8];
    unpack_hm(s0, s1, hv, mv);
    const int* start = dir ? start_out : start_in;
    const int* csr   = dir ? csr_out   : csr_in;
    int e0 = start[v], e1 = start[v + 1], len = e1 - e0;
    int e  = e0 + (len * qr) / 4;
    int hi = e0 + (len * (qr + 1)) / 4;
    float coef = -0.5f * grav[0];
    float acc[8] = {0.f, 0.f, 0.f, 0.f, 0.f, 0.f, 0.f, 0.f};
    for (; e + 1 < hi; e += 2) {
        int u0 = csr[e], u1 = csr[e + 1];
        const uint4* r0p = (const uint4*)(hm + (size_t)u0 * DD);
        const uint4* r1p = (const uint4*)(hm + (size_t)u1 * DD);
        uint4 x0 = r0p[0], x1 = r0p[1], y0 = r1p[0], y1 = r1p[1];
        float hu0[8], mu0[8], hu1[8], mu1[8];
        unpack_hm(x0, x1, hu0, mu0);
        unpack_hm(y0, y1, hu1, mu1);
        float d0[8], d1[8];
        float e20 = 0.f, S0 = 0.f, e21 = 0.f, S1 = 0.f;
#pragma unroll
        for (int k = 0; k < 8; k++) {
            d0[k] = hv[k] - hu0[k];
            d1[k] = hv[k] - hu1[k];
            e20 = fmaf(d0[k], d0[k], e20);
            e21 = fmaf(d1[k], d1[k], e21);
            S0 = fmaf(mv[k], mu0[k], S0);
            S1 = fmaf(mv[k], mu1[k], S1);
        }
        float r0 = rsqrtf(e20), r1 = rsqrtf(e21);
        float c0 = coef * S0 * r0 * r0 * r0;
        float c1 = coef * S1 * r1 * r1 * r1;
#pragma unroll
        for (int k = 0; k < 8; k++)
            acc[k] = fmaf(c0, d0[k], fmaf(c1, d1[k], acc[k]));
    }
    if (e < hi) {
        int u = csr[e];
        const uint4* rp = (const uint4*)(hm + (size_t)u * DD);
        uint4 x0 = rp[0], x1 = rp[1];
        float hu[8], mu[8];
        unpack_hm(x0, x1, hu, mu);
        float df[8];
        float e2 = 0.f, S = 0.f;
#pragma unroll
        for (int k = 0; k < 8; k++) {
            df[k] = hv[k] - hu[k];
            e2 = fmaf(df[k], df[k], e2);
            S = fmaf(mv[k], mu[k], S);
        }
        float r = rsqrtf(e2);
        float c = coef * S * r * r * r;
#pragma unroll
        for (int k = 0; k < 8; k++) acc[k] = fmaf(c, df[k], acc[k]);
    }
    red8(acc);   // combine the 8 subset threads via DPP
    if (sub == 0) {
        float4* gp = (float4*)(gh + (size_t)v * DD);
        gp[0] = make_float4(acc[0], acc[1], acc[2], acc[3]);
        gp[1] = make_float4(acc[4], acc[5], acc[6], acc[7]);
        float bv = b[v];
        __half2* bp = (__half2*)(bgh + (size_t)v * DD);
        bp[0] = __floats2half2_rn(bv * acc[0], bv * acc[1]);
        bp[1] = __floats2half2_rn(bv * acc[2], bv * acc[3]);
        bp[2] = __floats2half2_rn(bv * acc[4], bv * acc[5]);
        bp[3] = __floats2half2_rn(bv * acc[6], bv * acc[7]);
    }
}

// ===== FUSED: gq = AggOut(bgh) + MLP backward, 16 lanes/node, pair-dot2 =====
__launch_bounds__(256)
__global__ void k_bgh_mlp_bwd(const int* __restrict__ start, const int* __restrict__ csr,
                              const __half* __restrict__ bgh,
                              const float* __restrict__ agg1,
                              const float* __restrict__ a, const float* __restrict__ b,
                              const unsigned* __restrict__ Bp, const float* __restrict__ b1,
                              __half* __restrict__ gz1b, int N) {
    __shared__ unsigned sB[128 * BPITCH];   // 14 KB
    __shared__ float sb1[HH];
    for (int i = threadIdx.x; i < 128 * BPITCH; i += 256) sB[i] = Bp[i];
    for (int i = threadIdx.x; i < HH; i += 256) sb1[i] = b1[i];
    __syncthreads();
    int t = blockIdx.x * 256 + threadIdx.x;
    int v = t >> 4, l16 = t & 15, sub = (t >> 3) & 1, d = t & 7;
    if (v >= N) return;
    int e0 = start[v], e1 = start[v + 1];
    float gq[DD] = {0.f, 0.f, 0.f, 0.f, 0.f, 0.f, 0.f, 0.f};
    for (int e = e0 + l16; e < e1; e += 16) {
        uint4 r = *(const uint4*)(bgh + (size_t)csr[e] * DD);
        acc_h8(r, gq);
    }
    red16(gq);
    float bv = b[v], av = a[v];
    const float4* ap = (const float4*)(agg1 + (size_t)v * DD);
    float4 a0 = ap[0], a1 = ap[1];
    h2f zh[4], gqh[4];
    zh[0] = pkh(bv * a0.x, bv * a0.y); zh[1] = pkh(bv * a0.z, bv * a0.w);
    zh[2] = pkh(bv * a1.x, bv * a1.y); zh[3] = pkh(bv * a1.z, bv * a1.w);
#pragma unroll
    for (int k = 0; k < 4; k++) gqh[k] = pkh(gq[2 * k], gq[2 * k + 1]);
    float gz[DD] = {0.f, 0.f, 0.f, 0.f, 0.f, 0.f, 0.f, 0.f};
#pragma unroll
    for (int ci = 0; ci < 8; ci++) {
        int pid = ci * 16 + l16;
        const uint4* pw = (const uint4*)(sB + pid * BPITCH);
        uint4 w1a = pw[0], w1b = pw[1], w2r0 = pw[2], w2r1 = pw[3];
        uint4 g0p = pw[4], g1p = pw[5];
        int j0 = ci * 32 + l16;
        float u0 = sb1[j0], u1 = sb1[j0 + 16];
        u0 = dot2u(w1a.x, zh[0], u0); u0 = dot2u(w1a.y, zh[1], u0);
        u0 = dot2u(w1a.z, zh[2], u0); u0 = dot2u(w1a.w, zh[3], u0);
        u1 = dot2u(w1b.x, zh[0], u1); u1 = dot2u(w1b.y, zh[1], u1);
        u1 = dot2u(w1b.z, zh[2], u1); u1 = dot2u(w1b.w, zh[3], u1);
        float ga0 = dot2u(w2r0.x, gqh[0], 0.f);
        ga0 = dot2u(w2r0.y, gqh[1], ga0);
        ga0 = dot2u(w2r0.z, gqh[2], ga0);
        ga0 = dot2u(w2r0.w, gqh[3], ga0);
        float ga1 = dot2u(w2r1.x, gqh[0], 0.f);
        ga1 = dot2u(w2r1.y, gqh[1], ga1);
        ga1 = dot2u(w2r1.z, gqh[2], ga1);
        ga1 = dot2u(w2r1.w, gqh[3], ga1);
        float g0 = (u0 > 0.f) ? av * ga0 : 0.f;
        float g1 = (u1 > 0.f) ? av * ga1 : 0.f;
        h2f gg = pkh(g0, g1);
        gz[0] = dot2u(g0p.x, gg, gz[0]); gz[1] = dot2u(g0p.y, gg, gz[1]);
        gz[2] = dot2u(g0p.z, gg, gz[2]); gz[3] = dot2u(g0p.w, gg, gz[3]);
        gz[4] = dot2u(g1p.x, gg, gz[4]); gz[5] = dot2u(g1p.y, gg, gz[5]);
        gz[6] = dot2u(g1p.z, gg, gz[6]); gz[7] = dot2u(g1p.w, gg, gz[7]);
    }
    red16(gz);
    float out_l = gz[0];
#pragma unroll
    for (int k = 1; k < DD; k++) out_l = (d == k) ? gz[k] : out_l;
    if (!sub) gz1b[(size_t)v * DD + d] = __float2half(bv * out_l);
}

// out[:, :D] = gh + a * AggOut(gz1b); 8 thr/node
__launch_bounds__(256)
__global__ void k_out_node(const int* __restrict__ start, const int* __restrict__ csr,
                           const __half* __restrict__ gz1b, const float* __restrict__ gh,
                           const float* __restrict__ a, float* __restrict__ out, int N) {
    int t = blockIdx.x * 256 + threadIdx.x;
    int v = t >> 3, sub = t & 7;
    if (v >= N) return;
    int e0 = start[v], e1 = start[v + 1], len = e1 - e0;
    int lo = e0 + (len * sub) / 8, hi = e0 + (len * (sub + 1)) / 8;
    float acc[8] = {0.f, 0.f, 0.f, 0.f, 0.f, 0.f, 0.f, 0.f};
    gather_h8(csr, gz1b, lo, hi, acc);
    red8(acc);
    if (sub == 0) {
        float av = a[v];
        const float4* gp = (const float4*)(gh + (size_t)v * DD);
        float4 g0 = gp[0], g1 = gp[1];
        float4* op = (float4*)(out + (size_t)v * 2 * DD);
        op[0] = make_float4(fmaf(av, acc[0], g0.x), fmaf(av, acc[1], g0.y),
                            fmaf(av, acc[2], g0.z), fmaf(av, acc[3], g0.w));
        op[1] = make_float4(fmaf(av, acc[4], g1.x), fmaf(av, acc[5], g1.y),
                            fmaf(av, acc[6], g1.z), fmaf(av, acc[7], g1.w));
    }
}

// ============================== launch =====================================

extern "C" void kernel_launch(void* const* d_in, const int* in_sizes, int n_in,
                              void* d_out, int out_size, void* d_ws, size_t ws_size,
                              hipStream_t stream) {
    const float* q    = (const float*)d_in[0];
    const float* p    = (const float*)d_in[1];
    const float* M    = (const float*)d_in[2];
    const int*   src  = (const int*)d_in[3];
    const int*   dst  = (const int*)d_in[4];
    const float* W1   = (const float*)d_in[5];
    const float* b1   = (const float*)d_in[6];
    const float* W2   = (const float*)d_in[7];
    const float* b2   = (const float*)d_in[8];
    const float* grav = (const float*)d_in[9];
    float* out = (float*)d_out;

    int N = in_sizes[0] / DD;
    int E = in_sizes[3];
    size_t n = (size_t)N;
    int NB = (N + 511) >> 9;
    int NC = (E + CH - 1) / CH;

    // ---- data region (46N 4-byte words) ----
    float*   ws   = (float*)d_ws;
    float*   a_   = ws;             // N
    float*   b_   = ws + n;         // N
    __half*  qn   = (__half*)(ws + 2 * n);    // 8N half (4N words; region keeps 8N)
    float*   agg1 = ws + 10 * n;    // 8N f32 (live through bwd)
    float*   gh   = ws + 18 * n;    // 8N f32
    __half2* hm   = (__half2*)(ws + 26 * n);  // 8N half2 (8N words)
    __half*  ya   = (__half*)(ws + 34 * n);   // 8N half (4N words)
    __half*  bgh  = (__half*)(ws + 38 * n);   // 8N half (4N words)
    __half*  gz1b = (__half*)(ws + 42 * n);   // 8N half (4N words)

    // ---- int region ----
    int* iw        = (int*)(ws + 46 * n);
    int* csr_in    = iw;                       // E
    int* csr_out   = iw + (size_t)E;           // E
    int* start_in  = iw + 2 * (size_t)E;       // N+1
    int* start_out = start_in + n + 1;         // N+1
    int* binTotIn  = start_out + n + 1;        // 256
    int* binTotOut = binTotIn + 256;           // 256
    int* iwEnd     = binTotOut + 256;
    unsigned* Fp   = (unsigned*)iwEnd;         // 128*FPITCH = 2560 uints
    unsigned* Bp   = Fp + 128 * FPITCH;        // 128*BPITCH = 3584 uints
    int* cHistIn   = (int*)(Bp + 128 * BPITCH);  // NC*256 (becomes chunk-local bases)
    int* cHistOut  = cHistIn + (size_t)NC * 256; // NC*256
    int* intAfter  = cHistOut + (size_t)NC * 256;
    // partition scratch: both dirs alias the data region (dead during build)
    int* P_in  = (E <= 16 * (long long)n) ? (int*)ws            : intAfter;
    int* P_out = (E <= 16 * (long long)n) ? (int*)(ws + 16 * n) : intAfter + E;

    const int tb = 256;
    int gbN  = (N + tb - 1) / tb;
    int gb8  = (int)((8 * n + tb - 1) / tb);   // 8 threads/node
    int gb16 = (int)((16 * n + tb - 1) / tb);  // 16 lanes/node

    // CSR build (10 dispatches total in pipeline)
    k_coarse  <<<NC, tb, 0, stream>>>(src, dst, cHistIn, cHistOut, E);
    k_cscan1  <<<dim3(256, 2), tb, 0, stream>>>(cHistIn, cHistOut,
                                                binTotIn, binTotOut, NC);
    k_part2   <<<dim3(NC, 2), tb, 0, stream>>>(src, dst, cHistIn, cHistOut,
                                               binTotIn, binTotOut,
                                               P_in, P_out, E);
    k_fine2   <<<dim3(NB, 2), 512, 0, stream>>>(binTotIn, binTotOut, P_in, P_out,
                                                start_in, start_out, csr_in, csr_out, N);
    k_prep    <<<gbN, tb, 0, stream>>>(q, p, M, W1, W2, Fp, Bp, start_in, start_out,
                                       a_, b_, hm, qn, out, N, E);

    // forward: [agg1 = AggIn(a*q)] + [ya = a*(relu((b*agg1)@W1+b1)@W2)] fused
    k_agg_mlp_fwd<<<gb16, tb, 0, stream>>>(start_in, csr_in, qn, a_, b_,
                                           Fp, b1, agg1, ya, N);
    // h = b * AggIn(ya) + b2 + q  -> .x halves of hm
    k_h_node  <<<gb8, tb, 0, stream>>>(start_in, csr_in, ya, b_, q, b2, hm, N);
    // gravity gradient (8 threads/node, full records in-thread)
    k_gh4     <<<gb8, tb, 0, stream>>>(start_in, csr_in, start_out, csr_out,
                                       hm, b_, grav, gh, bgh, N);
    // [gq = AggOut(bgh)] + [gz1b = b*((a*(gq@W2^T)*relu')@W1^T)] fused
    k_bgh_mlp_bwd<<<gb16, tb, 0, stream>>>(start_out, csr_out, bgh, agg1, a_, b_,
                                           Bp, b1, gz1b, N);
    // dHdQ = gh + a * AggOut(gz1b)
    k_out_node<<<gb8, tb, 0, stream>>>(start_out, csr_out, gz1b, gh, a_, out, N);
}